// Round 12
// baseline (230.730 us; speedup 1.0000x reference)
//
#include <hip/hip_runtime.h>
#include <math.h>

#define NROWS 32768
#define NE    1024
#define CDIM  256
#define ZB_STRIDE 262144

#define ZQ_OFF   0
#define LOSS_OFF 8388608
#define PERP_OFF 8388609
#define ENC_OFF  8388610
#define IDX_OFF  41943042

#define THETA 1.0e-4f
// e scaled by 2^12 before fp16 conversion; -2*dot = -2^-11 * acc
#define NEG2_SCALE (-0.00048828125f)

typedef _Float16 f16x8 __attribute__((ext_vector_type(8)));
typedef __attribute__((ext_vector_type(4))) float f32x4;
typedef __attribute__((ext_vector_type(8))) unsigned short ushort8;

// RNE float -> fp16 bits
__device__ __forceinline__ unsigned short f2h(float x) {
  _Float16 h = (_Float16)x;
  unsigned short u;
  __builtin_memcpy(&u, &h, 2);
  return u;
}

// ---------------------------------------------------------------------------
// numpy-pairwise-exact sum of squares (stride 1)
__device__ __forceinline__ float np_sumsq_256_s1(const float* __restrict__ base) {
  float tot[2];
#pragma unroll
  for (int hh = 0; hh < 2; ++hh) {
    float r[8];
#pragma unroll
    for (int j = 0; j < 8; ++j) {
      float x = base[hh * 128 + j];
      r[j] = __fmul_rn(x, x);
    }
    for (int i = 8; i < 128; i += 8) {
#pragma unroll
      for (int j = 0; j < 8; ++j) {
        float x = base[hh * 128 + i + j];
        r[j] = __fadd_rn(r[j], __fmul_rn(x, x));
      }
    }
    tot[hh] = __fadd_rn(__fadd_rn(__fadd_rn(r[0], r[1]), __fadd_rn(r[2], r[3])),
                        __fadd_rn(__fadd_rn(r[4], r[5]), __fadd_rn(r[6], r[7])));
  }
  return __fadd_rn(tot[0], tot[1]);
}

// ---------------------------------------------------------------------------
// Fused emb prep (role-split):
// blocks [0,128): fp32 -> fp16*2^12 in MFMA-fragment order
// blocks [128,384): emb -> embT fp32 transpose (for repair)
// blocks [384,388): numpy-exact enorm
__global__ __launch_bounds__(256) void prep_e(const float* __restrict__ emb,
                                              unsigned short* __restrict__ ef16r,
                                              float* __restrict__ embT,
                                              float* __restrict__ enorm) {
  const int bid = blockIdx.x;
  if (bid < 128) {
    int cid = bid * 256 + threadIdx.x;   // 0..32767
    int e = cid >> 5, cc = cid & 31;
    int kc = cc >> 2, g = cc & 3;
    int c0 = kc * 32 + g * 8;
    ushort8 o;
#pragma unroll
    for (int el = 0; el < 8; ++el) o[el] = f2h(emb[(size_t)e * 256 + c0 + el] * 4096.0f);
    int et = e >> 7, wcb = (e >> 6) & 1, nj = (e >> 4) & 3, l15e = e & 15;
    size_t chunk = ((((size_t)et * 2 + wcb) * 8 + kc) * 4 + nj) * 64 + (size_t)g * 16 + l15e;
    *reinterpret_cast<ushort8*>(ef16r + (chunk << 3)) = o;
  } else if (bid < 384) {
    __shared__ float tile[32][33];
    int tb = bid - 128;
    int be = tb & 31, bc = tb >> 5;
    int tx = threadIdx.x & 31, ty = threadIdx.x >> 5;
#pragma unroll
    for (int i = 0; i < 4; ++i)
      tile[ty + 8 * i][tx] = emb[(size_t)(be * 32 + ty + 8 * i) * 256 + bc * 32 + tx];
    __syncthreads();
#pragma unroll
    for (int i = 0; i < 4; ++i)
      embT[(size_t)(bc * 32 + ty + 8 * i) * 1024 + be * 32 + tx] = tile[tx][ty + 8 * i];
  } else {
    int n = (bid - 384) * 256 + threadIdx.x;
    enorm[n] = np_sumsq_256_s1(emb + (size_t)n * CDIM);
  }
}

// ---------------------------------------------------------------------------
// z (b,c,h,w) fp32 -> zf16r (fragment order) + numpy-exact znorm (r4-verified
// accumulator tree).
__global__ __launch_bounds__(256) void convert_z_kernel(const float* __restrict__ z,
                                                        unsigned short* __restrict__ zf16r,
                                                        float* __restrict__ znorm) {
  __shared__ unsigned short T16[64][266];
  __shared__ float accsF[2][8][16][4];
  const int t = threadIdx.x;
  const int b = blockIdx.x >> 4, hwt = blockIdx.x & 15;
  const int hw0 = hwt * 64;
  const int hw4 = t & 15;
  const int jj = (t >> 4) & 7;
  const int hh = t >> 7;
  const float* zb = z + (size_t)b * ZB_STRIDE + hw0 + hw4 * 4;

  float rr[4];
#pragma unroll
  for (int i = 0; i < 16; ++i) {
    int c = hh * 128 + jj + 8 * i;
    float4 v = *reinterpret_cast<const float4*>(zb + (size_t)c * 1024);
    const float xv[4] = {v.x, v.y, v.z, v.w};
#pragma unroll
    for (int q = 0; q < 4; ++q) {
      float p = __fmul_rn(xv[q], xv[q]);
      rr[q] = (i == 0) ? p : __fadd_rn(rr[q], p);
      T16[hw4 * 4 + q][c] = f2h(xv[q]);
    }
  }
#pragma unroll
  for (int q = 0; q < 4; ++q) accsF[hh][jj][hw4][q] = rr[q];
  __syncthreads();

  if (t < 64) {
    const int h4 = t >> 2, cq = t & 3;
    float tot[2];
#pragma unroll
    for (int half = 0; half < 2; ++half) {
      float r[8];
#pragma unroll
      for (int j = 0; j < 8; ++j) r[j] = accsF[half][j][h4][cq];
      tot[half] = __fadd_rn(__fadd_rn(__fadd_rn(r[0], r[1]), __fadd_rn(r[2], r[3])),
                            __fadd_rn(__fadd_rn(r[4], r[5]), __fadd_rn(r[6], r[7])));
    }
    znorm[b * 1024 + hw0 + t] = __fadd_rn(tot[0], tot[1]);
  }

  // write phase: fragment order
  const int pw = b * 16 + hwt;
  const int panel = pw >> 1, wrh = pw & 1;
  const int l15w = t & 15, gw = (t >> 4) & 3, miw = t >> 6;
  const int rowW = miw * 16 + l15w;
#pragma unroll
  for (int kc = 0; kc < 8; ++kc) {
    ushort8 o;
#pragma unroll
    for (int el = 0; el < 8; ++el) o[el] = T16[rowW][kc * 32 + gw * 8 + el];
    size_t chunk = ((((size_t)panel * 2 + wrh) * 8 + kc) * 4 + miw) * 64 + (size_t)gw * 16 + l15w;
    *reinterpret_cast<ushort8*>(zf16r + (chunk << 3)) = o;
  }
}

// ---------------------------------------------------------------------------
// Swapped-operand full-e argmin, v9:
//  * acc = mfma(E_frag, Z_frag): acc rows = e, cols = n. Each lane owns its
//    n (col = lane&15) and holds 16 e-candidates per pass IN REGISTER ->
//    top-2 scan is pure VALU; cross-lane reduce = 2 butterfly steps over
//    g-groups (24 shfl/wave vs 192 in r11 — the r7/r8 counters showed
//    VALU:MFMA ~ 3:1, i.e. the old epilogue dominated).
//  * A- and B-fragment layouts are symmetric for 16x16x32 (lane&15 = row
//    resp. col, k = (lane>>4)*8+el) and our zf16r/ef16r use the identical
//    chunk formula -> operand swap needs NO layout change.
//  * One block (64 n x 8 e-slab-waves x 2 passes) covers ALL 1024 e ->
//    per-row idx/loss/flag finalized here; merge_kernel + pb arrays gone.
//  * d formula unchanged: d = fmaf(-2^-11, acc, fl(zn+en)); theta/repair
//    semantics identical (d differs only at ~1e-7 MFMA-rounding level).
__global__ __launch_bounds__(512, 4) void argmin_full(
    const unsigned short* __restrict__ zf16r, const unsigned short* __restrict__ ef16r,
    const float* __restrict__ znorm, const float* __restrict__ enorm,
    int* __restrict__ idx_out, float* __restrict__ loss_part,
    int* __restrict__ flag_cnt, int* __restrict__ flag_list) {
  __shared__ float sdd[64][9];
  __shared__ float sd2[64][9];
  __shared__ int   sdi[64][9];

  const int tid = threadIdx.x;
  const int lane = tid & 63, w = tid >> 6;     // 8 waves per block
  const int l15 = lane & 15, g = lane >> 4;

  // XCD-bijective: 512 blocks, one 64-row n-tile each; per-XCD z slab 2MB
  const int bid = blockIdx.x;
  const int nt = (bid & 7) * 64 + (bid >> 3);  // 0..511
  const int n0 = nt * 64;

  // z-fragments as B operand: base (panel*2+wrh) == nt
  const unsigned short* bP = zf16r + (size_t)nt * 16384 + lane * 8;

  float zn[4];
#pragma unroll
  for (int nj = 0; nj < 4; ++nj) zn[nj] = znorm[n0 + nj * 16 + l15];

  float bd[4], b2[4]; int bi[4];
#pragma unroll
  for (int nj = 0; nj < 4; ++nj) { bd[nj] = 3.4e38f; b2[nj] = 3.4e38f; bi[nj] = 0; }

  const f32x4 z4 = {0.f, 0.f, 0.f, 0.f};
#pragma unroll 1
  for (int p = 0; p < 2; ++p) {
    const int s = p * 8 + w;                   // e-slab 0..15, e = s*64 ..
    const unsigned short* aP = ef16r + (size_t)s * 16384 + lane * 8;

    f32x4 acc[4][4];
#pragma unroll
    for (int ei = 0; ei < 4; ++ei)
#pragma unroll
      for (int nj = 0; nj < 4; ++nj) acc[ei][nj] = z4;

#pragma unroll
    for (int kc = 0; kc < 8; ++kc) {
      f16x8 bv[4];
#pragma unroll
      for (int nj = 0; nj < 4; ++nj)
        bv[nj] = *reinterpret_cast<const f16x8*>(bP + (kc * 4 + nj) * 512);
#pragma unroll
      for (int ei = 0; ei < 4; ++ei) {
        f16x8 af = *reinterpret_cast<const f16x8*>(aP + (kc * 4 + ei) * 512);
#pragma unroll
        for (int nj = 0; nj < 4; ++nj)
          acc[ei][nj] = __builtin_amdgcn_mfma_f32_16x16x32_f16(af, bv[nj],
                                                               acc[ei][nj], 0, 0, 0);
      }
    }

    // in-lane top-2 scan: e ascending (p outer, ei then rg)
#pragma unroll
    for (int ei = 0; ei < 4; ++ei)
#pragma unroll
      for (int rg = 0; rg < 4; ++rg) {
        int e = s * 64 + ei * 16 + g * 4 + rg;
        float en = enorm[e];
#pragma unroll
        for (int nj = 0; nj < 4; ++nj) {
          float d = fmaf(NEG2_SCALE, acc[ei][nj][rg], __fadd_rn(zn[nj], en));
          if (d < bd[nj]) {
            b2[nj] = bd[nj]; bd[nj] = d; bi[nj] = e;
          } else if (d < b2[nj]) {
            b2[nj] = d;
          }
        }
      }
  }

  // cross-g butterfly (lanes {l15, l15+16, l15+32, l15+48} share n)
#pragma unroll
  for (int nj = 0; nj < 4; ++nj) {
#pragma unroll
    for (int m = 16; m <= 32; m <<= 1) {
      float od = __shfl_xor(bd[nj], m, 64);
      int   oi = __shfl_xor(bi[nj], m, 64);
      float o2 = __shfl_xor(b2[nj], m, 64);
      float hi = fmaxf(bd[nj], od);
      b2[nj] = fminf(fminf(b2[nj], o2), hi);
      if (od < bd[nj] || (od == bd[nj] && oi < bi[nj])) { bd[nj] = od; bi[nj] = oi; }
    }
    if (lane < 16) {
      sdd[nj * 16 + l15][w] = bd[nj];
      sdi[nj * 16 + l15][w] = bi[nj];
      sd2[nj * 16 + l15][w] = b2[nj];
    }
  }
  __syncthreads();

  // final 8-way merge per row (t < 64); exact first-index tie-break
  if (tid < 64) {
    float bdf = 3.4e38f; int bif = 0x7FFFFFFF; int bw = -1;
#pragma unroll
    for (int ww = 0; ww < 8; ++ww) {
      float d = sdd[tid][ww];
      int   i = sdi[tid][ww];
      if (d < bdf || (d == bdf && i < bif)) { bdf = d; bif = i; bw = ww; }
    }
    float b2f = 3.4e38f;
#pragma unroll
    for (int ww = 0; ww < 8; ++ww) {
      float v = (ww == bw) ? sd2[tid][ww] : sdd[tid][ww];
      b2f = fminf(b2f, v);
    }
    int n = n0 + tid;
    idx_out[n] = bif;
    loss_part[n] = bdf;
    if (b2f - bdf < THETA) {
      int pslot = atomicAdd(flag_cnt, 1);
      flag_list[pslot] = n;
    }
  }
}

// ---------------------------------------------------------------------------
// coalesced exact-fp32 repair: 4 flagged rows per block share one embT
// stream; per-row fmaf chain identical to the r1-certified arithmetic.
__global__ __launch_bounds__(256) void repair_kernel(
    const float* __restrict__ z, const float* __restrict__ embT,
    const float* __restrict__ znorm, const float* __restrict__ enorm,
    const int* __restrict__ flag_cnt, const int* __restrict__ flag_list,
    int* __restrict__ idx_out) {
  __shared__ float zrow[4][256];
  __shared__ float rd[256];
  __shared__ int   ri[256];
  const int t = threadIdx.x;
  const int cnt = flag_cnt[0] < NROWS ? flag_cnt[0] : NROWS;
  const int nquad = (cnt + 3) >> 2;
  const float4* embT4 = reinterpret_cast<const float4*>(embT);
  for (int j = blockIdx.x; j < nquad; j += gridDim.x) {
    int nr[4];
    __syncthreads();
#pragma unroll
    for (int r = 0; r < 4; ++r) {
      int jr = j * 4 + r;
      nr[r] = flag_list[jr < cnt ? jr : cnt - 1];
      zrow[r][t] = z[(size_t)(nr[r] >> 10) * ZB_STRIDE + (size_t)t * 1024 + (nr[r] & 1023)];
    }
    __syncthreads();
    float4 dot[4] = {{0.f,0.f,0.f,0.f},{0.f,0.f,0.f,0.f},{0.f,0.f,0.f,0.f},{0.f,0.f,0.f,0.f}};
    for (int k = 0; k < 256; ++k) {
      float4 v = embT4[k * 256 + t];
#pragma unroll
      for (int r = 0; r < 4; ++r) {
        float s = zrow[r][k];
        dot[r].x = fmaf(s, v.x, dot[r].x);
        dot[r].y = fmaf(s, v.y, dot[r].y);
        dot[r].z = fmaf(s, v.z, dot[r].z);
        dot[r].w = fmaf(s, v.w, dot[r].w);
      }
    }
#pragma unroll 1
    for (int r = 0; r < 4; ++r) {
      const float zn = znorm[nr[r]];
      float bd = 3.4e38f; int bi = 0;
      const float dv[4] = {dot[r].x, dot[r].y, dot[r].z, dot[r].w};
#pragma unroll
      for (int q = 0; q < 4; ++q) {
        int e = t * 4 + q;
        float d = __fsub_rn(__fadd_rn(zn, enorm[e]), __fmul_rn(2.0f, dv[q]));
        if (d < bd) { bd = d; bi = e; }
      }
      rd[t] = bd; ri[t] = bi;
      __syncthreads();
      for (int s2 = 128; s2 > 0; s2 >>= 1) {
        if (t < s2) {
          float od = rd[t + s2]; int oi = ri[t + s2];
          if (od < rd[t] || (od == rd[t] && oi < ri[t])) { rd[t] = od; ri[t] = oi; }
        }
        __syncthreads();
      }
      if (t == 0) idx_out[nr[r]] = ri[0];
      __syncthreads();
    }
  }
}

// ---------------------------------------------------------------------------
// Fused outputs (role-split): all 2048 blocks: one-hot streaming write;
// blocks [0,1024): z_q gather; blocks [1024,1152): idx-as-float + histogram.
__global__ __launch_bounds__(256) void outputs_kernel(const int* __restrict__ idx,
                                                      const float* __restrict__ emb,
                                                      float* __restrict__ out_enc,
                                                      float* __restrict__ out_idxf,
                                                      int* __restrict__ hist,
                                                      float* __restrict__ zq_out) {
  const int t = threadIdx.x;
  for (int i = blockIdx.x * 256 + t; i < NROWS * 256; i += 2048 * 256) {
    int n = i >> 8, j4 = i & 255;
    int e = idx[n];
    float4 v = {0.f, 0.f, 0.f, 0.f};
    if ((e >> 2) == j4) ((float*)&v)[e & 3] = 1.0f;
    reinterpret_cast<float4*>(out_enc)[i] = v;
  }
  if (blockIdx.x < 1024) {
    int bh = blockIdx.x;
    int b = bh >> 5, h = bh & 31;
    int ww = t & 31;
    int gg = t >> 5;
    int n = b * 1024 + h * 32 + ww;
    int e = idx[n];
    const float* eb = emb + (size_t)e * CDIM;
    float* ob = zq_out + (size_t)b * ZB_STRIDE + h * 32 + ww;
#pragma unroll
    for (int u = 0; u < 32; ++u) {
      int c = gg * 32 + u;
      ob[(size_t)c * 1024] = eb[c];
    }
  } else if (blockIdx.x < 1152) {
    int n = (blockIdx.x - 1024) * 256 + t;
    int e = idx[n];
    out_idxf[n] = (float)e;
    atomicAdd(&hist[e], 1);
  }
}

__global__ __launch_bounds__(256) void finalize_kernel(const float* __restrict__ loss_part,
                                                       const int* __restrict__ hist,
                                                       float* __restrict__ out_loss,
                                                       float* __restrict__ out_perp) {
  __shared__ float red[256];
  int t = threadIdx.x;
  float sum = 0.f;
  for (int i = t; i < NROWS; i += 256) sum += loss_part[i];
  red[t] = sum;
  __syncthreads();
  for (int s2 = 128; s2 > 0; s2 >>= 1) {
    if (t < s2) red[t] += red[t + s2];
    __syncthreads();
  }
  if (t == 0) out_loss[0] = 1.25f * (red[0] / 8388608.0f);
  __syncthreads();
  float hs = 0.f;
  for (int i = t; i < 1024; i += 256) {
    float em = (float)hist[i] / 32768.0f;
    hs += em * logf(em + 1e-10f);
  }
  red[t] = hs;
  __syncthreads();
  for (int s2 = 128; s2 > 0; s2 >>= 1) {
    if (t < s2) red[t] += red[t + s2];
    __syncthreads();
  }
  if (t == 0) out_perp[0] = expf(-red[0]);
}

// ---------------------------------------------------------------------------
extern "C" void kernel_launch(void* const* d_in, const int* in_sizes, int n_in,
                              void* d_out, int out_size, void* d_ws, size_t ws_size,
                              hipStream_t stream) {
  const float* z   = (const float*)d_in[0];
  const float* emb = (const float*)d_in[1];
  float* out = (float*)d_out;

  float* out_zq   = out + ZQ_OFF;
  float* out_loss = out + LOSS_OFF;
  float* out_perp = out + PERP_OFF;
  float* out_enc  = out + ENC_OFF;
  float* out_idxf = out + IDX_OFF;

  // workspace (small)
  int*   idx       = (int*)d_ws;                   // 32768
  int*   hist      = idx + NROWS;                  // 1024
  int*   flag_cnt  = hist + NE;                    // 4 (1 used)
  int*   flag_list = flag_cnt + 4;                 // 32768
  float* loss_part = (float*)(flag_list + NROWS);  // 32768
  float* znorm     = loss_part + NROWS;            // 32768
  float* enorm     = znorm + NROWS;                // 1024

  // staging buffers carved from the one-hot output region (overwritten later)
  unsigned short* zf16r = (unsigned short*)(out_enc + 2);    // 8388608 u16 (16B-aligned)
  unsigned short* ef16r = zf16r + (size_t)NROWS * CDIM;      // 262144 u16
  float*          embT  = (float*)(ef16r + (size_t)NE * CDIM);// 262144 f32

  // hist (NE ints) and flag_cnt (adjacent) in one memset
  hipMemsetAsync(hist, 0, (NE + 1) * sizeof(int), stream);

  convert_z_kernel<<<512, 256, 0, stream>>>(z, zf16r, znorm);
  prep_e<<<388, 256, 0, stream>>>(emb, ef16r, embT, enorm);
  argmin_full<<<512, 512, 0, stream>>>(zf16r, ef16r, znorm, enorm,
                                       idx, loss_part, flag_cnt, flag_list);
  repair_kernel<<<256, 256, 0, stream>>>(z, embT, znorm, enorm, flag_cnt, flag_list, idx);
  outputs_kernel<<<2048, 256, 0, stream>>>(idx, emb, out_enc, out_idxf, hist, out_zq);
  finalize_kernel<<<1, 256, 0, stream>>>(loss_part, hist, out_loss, out_perp);
}

// Round 13
// 179.867 us; speedup vs baseline: 1.2828x; 1.2828x over previous
//
#include <hip/hip_runtime.h>
#include <math.h>

#define NROWS 32768
#define NE    1024
#define CDIM  256
#define ZB_STRIDE 262144

#define ZQ_OFF   0
#define LOSS_OFF 8388608
#define PERP_OFF 8388609
#define ENC_OFF  8388610
#define IDX_OFF  41943042

#define THETA 1.0e-4f
// e scaled by 2^12 before fp16 conversion; -2*dot = -2^-11 * acc
#define NEG2_SCALE (-0.00048828125f)

typedef _Float16 f16x8 __attribute__((ext_vector_type(8)));
typedef __attribute__((ext_vector_type(4))) float f32x4;
typedef __attribute__((ext_vector_type(8))) unsigned short ushort8;

// RNE float -> fp16 bits
__device__ __forceinline__ unsigned short f2h(float x) {
  _Float16 h = (_Float16)x;
  unsigned short u;
  __builtin_memcpy(&u, &h, 2);
  return u;
}

// ---------------------------------------------------------------------------
// numpy-pairwise-exact sum of squares (stride 1)
__device__ __forceinline__ float np_sumsq_256_s1(const float* __restrict__ base) {
  float tot[2];
#pragma unroll
  for (int hh = 0; hh < 2; ++hh) {
    float r[8];
#pragma unroll
    for (int j = 0; j < 8; ++j) {
      float x = base[hh * 128 + j];
      r[j] = __fmul_rn(x, x);
    }
    for (int i = 8; i < 128; i += 8) {
#pragma unroll
      for (int j = 0; j < 8; ++j) {
        float x = base[hh * 128 + i + j];
        r[j] = __fadd_rn(r[j], __fmul_rn(x, x));
      }
    }
    tot[hh] = __fadd_rn(__fadd_rn(__fadd_rn(r[0], r[1]), __fadd_rn(r[2], r[3])),
                        __fadd_rn(__fadd_rn(r[4], r[5]), __fadd_rn(r[6], r[7])));
  }
  return __fadd_rn(tot[0], tot[1]);
}

// ---------------------------------------------------------------------------
// Fused emb prep (role-split):
// blocks [0,128): fp32 -> fp16*2^12 in MFMA-fragment order
// blocks [128,384): emb -> embT fp32 transpose (for repair)
// blocks [384,388): numpy-exact enorm
__global__ __launch_bounds__(256) void prep_e(const float* __restrict__ emb,
                                              unsigned short* __restrict__ ef16r,
                                              float* __restrict__ embT,
                                              float* __restrict__ enorm) {
  const int bid = blockIdx.x;
  if (bid < 128) {
    int cid = bid * 256 + threadIdx.x;   // 0..32767
    int e = cid >> 5, cc = cid & 31;
    int kc = cc >> 2, g = cc & 3;
    int c0 = kc * 32 + g * 8;
    ushort8 o;
#pragma unroll
    for (int el = 0; el < 8; ++el) o[el] = f2h(emb[(size_t)e * 256 + c0 + el] * 4096.0f);
    int et = e >> 7, wcb = (e >> 6) & 1, nj = (e >> 4) & 3, l15e = e & 15;
    size_t chunk = ((((size_t)et * 2 + wcb) * 8 + kc) * 4 + nj) * 64 + (size_t)g * 16 + l15e;
    *reinterpret_cast<ushort8*>(ef16r + (chunk << 3)) = o;
  } else if (bid < 384) {
    __shared__ float tile[32][33];
    int tb = bid - 128;
    int be = tb & 31, bc = tb >> 5;
    int tx = threadIdx.x & 31, ty = threadIdx.x >> 5;
#pragma unroll
    for (int i = 0; i < 4; ++i)
      tile[ty + 8 * i][tx] = emb[(size_t)(be * 32 + ty + 8 * i) * 256 + bc * 32 + tx];
    __syncthreads();
#pragma unroll
    for (int i = 0; i < 4; ++i)
      embT[(size_t)(bc * 32 + ty + 8 * i) * 1024 + be * 32 + tx] = tile[tx][ty + 8 * i];
  } else {
    int n = (bid - 384) * 256 + threadIdx.x;
    enorm[n] = np_sumsq_256_s1(emb + (size_t)n * CDIM);
  }
}

// ---------------------------------------------------------------------------
// z (b,c,h,w) fp32 -> zf16r (fragment order) + numpy-exact znorm (r4-verified
// accumulator tree).
__global__ __launch_bounds__(256) void convert_z_kernel(const float* __restrict__ z,
                                                        unsigned short* __restrict__ zf16r,
                                                        float* __restrict__ znorm) {
  __shared__ unsigned short T16[64][266];
  __shared__ float accsF[2][8][16][4];
  const int t = threadIdx.x;
  const int b = blockIdx.x >> 4, hwt = blockIdx.x & 15;
  const int hw0 = hwt * 64;
  const int hw4 = t & 15;
  const int jj = (t >> 4) & 7;
  const int hh = t >> 7;
  const float* zb = z + (size_t)b * ZB_STRIDE + hw0 + hw4 * 4;

  float rr[4];
#pragma unroll
  for (int i = 0; i < 16; ++i) {
    int c = hh * 128 + jj + 8 * i;
    float4 v = *reinterpret_cast<const float4*>(zb + (size_t)c * 1024);
    const float xv[4] = {v.x, v.y, v.z, v.w};
#pragma unroll
    for (int q = 0; q < 4; ++q) {
      float p = __fmul_rn(xv[q], xv[q]);
      rr[q] = (i == 0) ? p : __fadd_rn(rr[q], p);
      T16[hw4 * 4 + q][c] = f2h(xv[q]);
    }
  }
#pragma unroll
  for (int q = 0; q < 4; ++q) accsF[hh][jj][hw4][q] = rr[q];
  __syncthreads();

  if (t < 64) {
    const int h4 = t >> 2, cq = t & 3;
    float tot[2];
#pragma unroll
    for (int half = 0; half < 2; ++half) {
      float r[8];
#pragma unroll
      for (int j = 0; j < 8; ++j) r[j] = accsF[half][j][h4][cq];
      tot[half] = __fadd_rn(__fadd_rn(__fadd_rn(r[0], r[1]), __fadd_rn(r[2], r[3])),
                            __fadd_rn(__fadd_rn(r[4], r[5]), __fadd_rn(r[6], r[7])));
    }
    znorm[b * 1024 + hw0 + t] = __fadd_rn(tot[0], tot[1]);
  }

  // write phase: fragment order
  const int pw = b * 16 + hwt;
  const int panel = pw >> 1, wrh = pw & 1;
  const int l15w = t & 15, gw = (t >> 4) & 3, miw = t >> 6;
  const int rowW = miw * 16 + l15w;
#pragma unroll
  for (int kc = 0; kc < 8; ++kc) {
    ushort8 o;
#pragma unroll
    for (int el = 0; el < 8; ++el) o[el] = T16[rowW][kc * 32 + gw * 8 + el];
    size_t chunk = ((((size_t)panel * 2 + wrh) * 8 + kc) * 4 + miw) * 64 + (size_t)gw * 16 + l15w;
    *reinterpret_cast<ushort8*>(zf16r + (chunk << 3)) = o;
  }
}

// ---------------------------------------------------------------------------
// Swapped-operand tiled argmin, v10 = r11 memory structure + r12 orientation:
//  * block = 128 e x 128 n, grid 2048, XCD-bijective (nb inner: 8 co-XCD
//    blocks share one z panel -> FETCH ~21 MB, r5/r11-verified), lean
//    single-buffered K-loop, 4 waves/SIMD.
//  * acc = mfma(E_frag, Z_frag): rows = e, cols = n. Lane owns n (col=l15);
//    16 e-candidates per (nj) in-register -> top-2 = pure VALU scan +
//    2-step cross-g butterfly + one 2-way cross-wr LDS merge (24 shfl/wave
//    vs 192 in r11 -- r7/r8 counters showed 3:1 VALU:MFMA = old epilogue).
//    r12 proved the operand swap bit-correct; r12's memory thrash (all-E
//    per block, FETCH 148MB) is what this reverts.
//  * d formula / theta / first-index tie-break semantics unchanged.
__global__ __launch_bounds__(256, 4) void argmin_tile(
    const unsigned short* __restrict__ zf16r, const unsigned short* __restrict__ ef16r,
    const float* __restrict__ znorm, const float* __restrict__ enorm,
    float* __restrict__ pbd, int* __restrict__ pbi, float* __restrict__ pb2) {
  __shared__ float sdd[128][2];
  __shared__ float sd2[128][2];
  __shared__ int   sdi[128][2];

  const int tid = threadIdx.x;
  const int lane = tid & 63, w = tid >> 6;
  const int wr = w >> 1, wc = w & 1;     // wr = e-half, wc = n-half
  const int l15 = lane & 15, g = lane >> 4;

  // XCD-bijective swizzle: xcd = bid&7; 32 n-panels x 8 e-tiles per XCD
  const int bid = blockIdx.x;
  const int nb = (bid >> 3) & 7;             // e-tile (0..7), 128 e each
  const int mb = (bid & 7) * 32 + (bid >> 6);// n-panel (0..255), 128 n each
  const int n0 = mb * 128;
  const int e0 = nb * 128;

  // fragment pointers (u16 units); advance 2048 u16 (4KB) per kc
  // A = E slab (e/64 = nb*2+wr), B = z slab (n/64 = mb*2+wc)
  const unsigned short* aP = ef16r + (size_t)(nb * 2 + wr) * 16384 + lane * 8;
  const unsigned short* bP = zf16r + (size_t)(mb * 2 + wc) * 16384 + lane * 8;

  f32x4 acc[4][4];
  const f32x4 z4 = {0.f, 0.f, 0.f, 0.f};
#pragma unroll
  for (int ei = 0; ei < 4; ++ei)
#pragma unroll
    for (int nj = 0; nj < 4; ++nj) acc[ei][nj] = z4;

#pragma unroll 1
  for (int kc = 0; kc < 8; ++kc) {
    f16x8 af[4], bv[4];
#pragma unroll
    for (int ei = 0; ei < 4; ++ei)
      af[ei] = *reinterpret_cast<const f16x8*>(aP + ei * 512);
#pragma unroll
    for (int nj = 0; nj < 4; ++nj)
      bv[nj] = *reinterpret_cast<const f16x8*>(bP + nj * 512);
    aP += 2048; bP += 2048;
#pragma unroll
    for (int ei = 0; ei < 4; ++ei)
#pragma unroll
      for (int nj = 0; nj < 4; ++nj)
        acc[ei][nj] = __builtin_amdgcn_mfma_f32_16x16x32_f16(af[ei], bv[nj],
                                                             acc[ei][nj], 0, 0, 0);
  }

  // epilogue: lane owns n = n0 + wc*64 + nj*16 + l15; e = e0 + wr*64 +
  // ei*16 + g*4 + rg. In-lane ascending-e top-2 scan (pure VALU).
  const int n0w = n0 + wc * 64;
  const int e0w = e0 + wr * 64;
  float zn[4];
#pragma unroll
  for (int nj = 0; nj < 4; ++nj) zn[nj] = znorm[n0w + nj * 16 + l15];

  float bd[4], b2[4]; int bi[4];
#pragma unroll
  for (int nj = 0; nj < 4; ++nj) { bd[nj] = 3.4e38f; b2[nj] = 3.4e38f; bi[nj] = 0; }

#pragma unroll
  for (int ei = 0; ei < 4; ++ei)
#pragma unroll
    for (int rg = 0; rg < 4; ++rg) {
      int e = e0w + ei * 16 + g * 4 + rg;
      float en = enorm[e];
#pragma unroll
      for (int nj = 0; nj < 4; ++nj) {
        float d = fmaf(NEG2_SCALE, acc[ei][nj][rg], __fadd_rn(zn[nj], en));
        if (d < bd[nj]) {
          b2[nj] = bd[nj]; bd[nj] = d; bi[nj] = e;
        } else if (d < b2[nj]) {
          b2[nj] = d;
        }
      }
    }

  // cross-g butterfly (lanes {l15+16g} share n; different e-subsets)
#pragma unroll
  for (int nj = 0; nj < 4; ++nj) {
#pragma unroll
    for (int m = 16; m <= 32; m <<= 1) {
      float od = __shfl_xor(bd[nj], m, 64);
      int   oi = __shfl_xor(bi[nj], m, 64);
      float o2 = __shfl_xor(b2[nj], m, 64);
      float hi = fmaxf(bd[nj], od);
      b2[nj] = fminf(fminf(b2[nj], o2), hi);
      if (od < bd[nj] || (od == bd[nj] && oi < bi[nj])) { bd[nj] = od; bi[nj] = oi; }
    }
    if (g == 0) {
      int nl = wc * 64 + nj * 16 + l15;   // block-local n (0..127)
      sdd[nl][wr] = bd[nj];
      sdi[nl][wr] = bi[nj];
      sd2[nl][wr] = b2[nj];
    }
  }
  __syncthreads();

  // cross-wr 2-way merge (e-halves), exact first-index tie-break
  if (tid < 128) {
    float d0 = sdd[tid][0], d1 = sdd[tid][1];
    int   i0 = sdi[tid][0], i1 = sdi[tid][1];
    float s0 = sd2[tid][0], s1 = sd2[tid][1];
    float bdf; int bif;
    if (d1 < d0 || (d1 == d0 && i1 < i0)) { bdf = d1; bif = i1; } else { bdf = d0; bif = i0; }
    float b2f = fminf(fminf(s0, s1), fmaxf(d0, d1));
    size_t o = (size_t)(n0 + tid) * 8 + nb;
    pbd[o] = bdf; pbi[o] = bif; pb2[o] = b2f;
  }
}

// ---------------------------------------------------------------------------
// merge 8 per-block top-2 candidates per row; exact first-index tie-break
__global__ __launch_bounds__(256) void merge_kernel(
    const float* __restrict__ pbd, const int* __restrict__ pbi,
    const float* __restrict__ pb2,
    int* __restrict__ idx_out, float* __restrict__ loss_part,
    int* __restrict__ flag_cnt, int* __restrict__ flag_list) {
  int n = blockIdx.x * 256 + threadIdx.x;
  float bd = 3.4e38f; int bi = 0x7FFFFFFF; int bnb = -1;
#pragma unroll
  for (int nb = 0; nb < 8; ++nb) {
    float d = pbd[(size_t)n * 8 + nb];
    int   i = pbi[(size_t)n * 8 + nb];
    if (d < bd || (d == bd && i < bi)) { bd = d; bi = i; bnb = nb; }
  }
  float b2 = 3.4e38f;
#pragma unroll
  for (int nb = 0; nb < 8; ++nb) {
    float v = (nb == bnb) ? pb2[(size_t)n * 8 + nb] : pbd[(size_t)n * 8 + nb];
    b2 = fminf(b2, v);
  }
  idx_out[n] = bi;
  loss_part[n] = bd;
  if (b2 - bd < THETA) {
    int p = atomicAdd(flag_cnt, 1);
    flag_list[p] = n;
  }
}

// ---------------------------------------------------------------------------
// coalesced exact-fp32 repair: 4 flagged rows per block share one embT
// stream; per-row fmaf chain identical to the r1-certified arithmetic.
__global__ __launch_bounds__(256) void repair_kernel(
    const float* __restrict__ z, const float* __restrict__ embT,
    const float* __restrict__ znorm, const float* __restrict__ enorm,
    const int* __restrict__ flag_cnt, const int* __restrict__ flag_list,
    int* __restrict__ idx_out) {
  __shared__ float zrow[4][256];
  __shared__ float rd[256];
  __shared__ int   ri[256];
  const int t = threadIdx.x;
  const int cnt = flag_cnt[0] < NROWS ? flag_cnt[0] : NROWS;
  const int nquad = (cnt + 3) >> 2;
  const float4* embT4 = reinterpret_cast<const float4*>(embT);
  for (int j = blockIdx.x; j < nquad; j += gridDim.x) {
    int nr[4];
    __syncthreads();
#pragma unroll
    for (int r = 0; r < 4; ++r) {
      int jr = j * 4 + r;
      nr[r] = flag_list[jr < cnt ? jr : cnt - 1];
      zrow[r][t] = z[(size_t)(nr[r] >> 10) * ZB_STRIDE + (size_t)t * 1024 + (nr[r] & 1023)];
    }
    __syncthreads();
    float4 dot[4] = {{0.f,0.f,0.f,0.f},{0.f,0.f,0.f,0.f},{0.f,0.f,0.f,0.f},{0.f,0.f,0.f,0.f}};
    for (int k = 0; k < 256; ++k) {
      float4 v = embT4[k * 256 + t];
#pragma unroll
      for (int r = 0; r < 4; ++r) {
        float s = zrow[r][k];
        dot[r].x = fmaf(s, v.x, dot[r].x);
        dot[r].y = fmaf(s, v.y, dot[r].y);
        dot[r].z = fmaf(s, v.z, dot[r].z);
        dot[r].w = fmaf(s, v.w, dot[r].w);
      }
    }
#pragma unroll 1
    for (int r = 0; r < 4; ++r) {
      const float zn = znorm[nr[r]];
      float bd = 3.4e38f; int bi = 0;
      const float dv[4] = {dot[r].x, dot[r].y, dot[r].z, dot[r].w};
#pragma unroll
      for (int q = 0; q < 4; ++q) {
        int e = t * 4 + q;
        float d = __fsub_rn(__fadd_rn(zn, enorm[e]), __fmul_rn(2.0f, dv[q]));
        if (d < bd) { bd = d; bi = e; }
      }
      rd[t] = bd; ri[t] = bi;
      __syncthreads();
      for (int s2 = 128; s2 > 0; s2 >>= 1) {
        if (t < s2) {
          float od = rd[t + s2]; int oi = ri[t + s2];
          if (od < rd[t] || (od == rd[t] && oi < ri[t])) { rd[t] = od; ri[t] = oi; }
        }
        __syncthreads();
      }
      if (t == 0) idx_out[nr[r]] = ri[0];
      __syncthreads();
    }
  }
}

// ---------------------------------------------------------------------------
// Fused outputs (role-split): all 2048 blocks: one-hot streaming write;
// blocks [0,1024): z_q gather; blocks [1024,1152): idx-as-float + histogram.
__global__ __launch_bounds__(256) void outputs_kernel(const int* __restrict__ idx,
                                                      const float* __restrict__ emb,
                                                      float* __restrict__ out_enc,
                                                      float* __restrict__ out_idxf,
                                                      int* __restrict__ hist,
                                                      float* __restrict__ zq_out) {
  const int t = threadIdx.x;
  for (int i = blockIdx.x * 256 + t; i < NROWS * 256; i += 2048 * 256) {
    int n = i >> 8, j4 = i & 255;
    int e = idx[n];
    float4 v = {0.f, 0.f, 0.f, 0.f};
    if ((e >> 2) == j4) ((float*)&v)[e & 3] = 1.0f;
    reinterpret_cast<float4*>(out_enc)[i] = v;
  }
  if (blockIdx.x < 1024) {
    int bh = blockIdx.x;
    int b = bh >> 5, h = bh & 31;
    int ww = t & 31;
    int gg = t >> 5;
    int n = b * 1024 + h * 32 + ww;
    int e = idx[n];
    const float* eb = emb + (size_t)e * CDIM;
    float* ob = zq_out + (size_t)b * ZB_STRIDE + h * 32 + ww;
#pragma unroll
    for (int u = 0; u < 32; ++u) {
      int c = gg * 32 + u;
      ob[(size_t)c * 1024] = eb[c];
    }
  } else if (blockIdx.x < 1152) {
    int n = (blockIdx.x - 1024) * 256 + t;
    int e = idx[n];
    out_idxf[n] = (float)e;
    atomicAdd(&hist[e], 1);
  }
}

__global__ __launch_bounds__(256) void finalize_kernel(const float* __restrict__ loss_part,
                                                       const int* __restrict__ hist,
                                                       float* __restrict__ out_loss,
                                                       float* __restrict__ out_perp) {
  __shared__ float red[256];
  int t = threadIdx.x;
  float sum = 0.f;
  for (int i = t; i < NROWS; i += 256) sum += loss_part[i];
  red[t] = sum;
  __syncthreads();
  for (int s2 = 128; s2 > 0; s2 >>= 1) {
    if (t < s2) red[t] += red[t + s2];
    __syncthreads();
  }
  if (t == 0) out_loss[0] = 1.25f * (red[0] / 8388608.0f);
  __syncthreads();
  float hs = 0.f;
  for (int i = t; i < 1024; i += 256) {
    float em = (float)hist[i] / 32768.0f;
    hs += em * logf(em + 1e-10f);
  }
  red[t] = hs;
  __syncthreads();
  for (int s2 = 128; s2 > 0; s2 >>= 1) {
    if (t < s2) red[t] += red[t + s2];
    __syncthreads();
  }
  if (t == 0) out_perp[0] = expf(-red[0]);
}

// ---------------------------------------------------------------------------
extern "C" void kernel_launch(void* const* d_in, const int* in_sizes, int n_in,
                              void* d_out, int out_size, void* d_ws, size_t ws_size,
                              hipStream_t stream) {
  const float* z   = (const float*)d_in[0];
  const float* emb = (const float*)d_in[1];
  float* out = (float*)d_out;

  float* out_zq   = out + ZQ_OFF;
  float* out_loss = out + LOSS_OFF;
  float* out_perp = out + PERP_OFF;
  float* out_enc  = out + ENC_OFF;
  float* out_idxf = out + IDX_OFF;

  // workspace (small)
  int*   idx       = (int*)d_ws;                   // 32768
  int*   hist      = idx + NROWS;                  // 1024
  int*   flag_cnt  = hist + NE;                    // 4 (1 used)
  int*   flag_list = flag_cnt + 4;                 // 32768
  float* loss_part = (float*)(flag_list + NROWS);  // 32768
  float* znorm     = loss_part + NROWS;            // 32768
  float* enorm     = znorm + NROWS;                // 1024

  // staging buffers carved from the one-hot output region (overwritten later)
  unsigned short* zf16r = (unsigned short*)(out_enc + 2);    // 8388608 u16 (16B-aligned)
  unsigned short* ef16r = zf16r + (size_t)NROWS * CDIM;      // 262144 u16
  float*          embT  = (float*)(ef16r + (size_t)NE * CDIM);// 262144 f32
  float*          pbd   = embT + 262144;                     // 262144 f32
  int*            pbi   = (int*)(pbd + 262144);              // 262144 i32
  float*          pb2   = (float*)(pbi + 262144);            // 262144 f32

  // hist (NE ints) and flag_cnt (adjacent) in one memset
  hipMemsetAsync(hist, 0, (NE + 1) * sizeof(int), stream);

  convert_z_kernel<<<512, 256, 0, stream>>>(z, zf16r, znorm);
  prep_e<<<388, 256, 0, stream>>>(emb, ef16r, embT, enorm);
  argmin_tile<<<2048, 256, 0, stream>>>(zf16r, ef16r, znorm, enorm, pbd, pbi, pb2);
  merge_kernel<<<NROWS / 256, 256, 0, stream>>>(pbd, pbi, pb2, idx, loss_part, flag_cnt, flag_list);
  repair_kernel<<<256, 256, 0, stream>>>(z, embT, znorm, enorm, flag_cnt, flag_list, idx);
  outputs_kernel<<<2048, 256, 0, stream>>>(idx, emb, out_enc, out_idxf, hist, out_zq);
  finalize_kernel<<<1, 256, 0, stream>>>(loss_part, hist, out_loss, out_perp);
}

// Round 14
// 157.410 us; speedup vs baseline: 1.4658x; 1.1427x over previous
//
#include <hip/hip_runtime.h>
#include <math.h>

#define NROWS 32768
#define NE    1024
#define CDIM  256
#define ZB_STRIDE 262144

#define ZQ_OFF   0
#define LOSS_OFF 8388608
#define PERP_OFF 8388609
#define ENC_OFF  8388610
#define IDX_OFF  41943042

#define THETA 1.0e-4f
// e scaled by 2^12 before fp16 conversion; -2*dot = -2^-11 * acc
#define NEG2_SCALE (-0.00048828125f)

typedef _Float16 f16x8 __attribute__((ext_vector_type(8)));
typedef __attribute__((ext_vector_type(4))) float f32x4;
typedef __attribute__((ext_vector_type(8))) unsigned short ushort8;

// RNE float -> fp16 bits
__device__ __forceinline__ unsigned short f2h(float x) {
  _Float16 h = (_Float16)x;
  unsigned short u;
  __builtin_memcpy(&u, &h, 2);
  return u;
}

// ---------------------------------------------------------------------------
// numpy-pairwise-exact sum of squares (stride 1)
__device__ __forceinline__ float np_sumsq_256_s1(const float* __restrict__ base) {
  float tot[2];
#pragma unroll
  for (int hh = 0; hh < 2; ++hh) {
    float r[8];
#pragma unroll
    for (int j = 0; j < 8; ++j) {
      float x = base[hh * 128 + j];
      r[j] = __fmul_rn(x, x);
    }
    for (int i = 8; i < 128; i += 8) {
#pragma unroll
      for (int j = 0; j < 8; ++j) {
        float x = base[hh * 128 + i + j];
        r[j] = __fadd_rn(r[j], __fmul_rn(x, x));
      }
    }
    tot[hh] = __fadd_rn(__fadd_rn(__fadd_rn(r[0], r[1]), __fadd_rn(r[2], r[3])),
                        __fadd_rn(__fadd_rn(r[4], r[5]), __fadd_rn(r[6], r[7])));
  }
  return __fadd_rn(tot[0], tot[1]);
}

// ---------------------------------------------------------------------------
// Fused convert: blocks [0,512) = convert_z role (r4-certified norm tree +
// fragment-order fp16 write); [512,640) = convert_e fragment role;
// [640,896) = embT transpose; [896,900) = enorm.
__global__ __launch_bounds__(256) void convert_all(const float* __restrict__ z,
                                                   const float* __restrict__ emb,
                                                   unsigned short* __restrict__ zf16r,
                                                   unsigned short* __restrict__ ef16r,
                                                   float* __restrict__ embT,
                                                   float* __restrict__ znorm,
                                                   float* __restrict__ enorm) {
  __shared__ __align__(16) char smem[38144];
  const int bid = blockIdx.x;
  const int t = threadIdx.x;

  if (bid < 512) {
    // ---- convert_z role (identical math to r13's certified kernel) ----
    unsigned short (*T16)[266] = reinterpret_cast<unsigned short (*)[266]>(smem);
    float (*accsF)[8][16][4] = reinterpret_cast<float (*)[8][16][4]>(smem + 34048);
    const int b = bid >> 4, hwt = bid & 15;
    const int hw0 = hwt * 64;
    const int hw4 = t & 15;
    const int jj = (t >> 4) & 7;
    const int hh = t >> 7;
    const float* zb = z + (size_t)b * ZB_STRIDE + hw0 + hw4 * 4;

    float rr[4];
#pragma unroll
    for (int i = 0; i < 16; ++i) {
      int c = hh * 128 + jj + 8 * i;
      float4 v = *reinterpret_cast<const float4*>(zb + (size_t)c * 1024);
      const float xv[4] = {v.x, v.y, v.z, v.w};
#pragma unroll
      for (int q = 0; q < 4; ++q) {
        float p = __fmul_rn(xv[q], xv[q]);
        rr[q] = (i == 0) ? p : __fadd_rn(rr[q], p);
        T16[hw4 * 4 + q][c] = f2h(xv[q]);
      }
    }
#pragma unroll
    for (int q = 0; q < 4; ++q) accsF[hh][jj][hw4][q] = rr[q];
    __syncthreads();

    if (t < 64) {
      const int h4 = t >> 2, cq = t & 3;
      float tot[2];
#pragma unroll
      for (int half = 0; half < 2; ++half) {
        float r[8];
#pragma unroll
        for (int j = 0; j < 8; ++j) r[j] = accsF[half][j][h4][cq];
        tot[half] = __fadd_rn(__fadd_rn(__fadd_rn(r[0], r[1]), __fadd_rn(r[2], r[3])),
                              __fadd_rn(__fadd_rn(r[4], r[5]), __fadd_rn(r[6], r[7])));
      }
      znorm[b * 1024 + hw0 + t] = __fadd_rn(tot[0], tot[1]);
    }

    const int pw = b * 16 + hwt;
    const int panel = pw >> 1, wrh = pw & 1;
    const int l15w = t & 15, gw = (t >> 4) & 3, miw = t >> 6;
    const int rowW = miw * 16 + l15w;
#pragma unroll
    for (int kc = 0; kc < 8; ++kc) {
      ushort8 o;
#pragma unroll
      for (int el = 0; el < 8; ++el) o[el] = T16[rowW][kc * 32 + gw * 8 + el];
      size_t chunk = ((((size_t)panel * 2 + wrh) * 8 + kc) * 4 + miw) * 64 + (size_t)gw * 16 + l15w;
      *reinterpret_cast<ushort8*>(zf16r + (chunk << 3)) = o;
    }
  } else if (bid < 640) {
    // ---- convert_e fragment role ----
    int cid = (bid - 512) * 256 + t;
    int e = cid >> 5, cc = cid & 31;
    int kc = cc >> 2, g = cc & 3;
    int c0 = kc * 32 + g * 8;
    ushort8 o;
#pragma unroll
    for (int el = 0; el < 8; ++el) o[el] = f2h(emb[(size_t)e * 256 + c0 + el] * 4096.0f);
    int et = e >> 7, wcb = (e >> 6) & 1, nj = (e >> 4) & 3, l15e = e & 15;
    size_t chunk = ((((size_t)et * 2 + wcb) * 8 + kc) * 4 + nj) * 64 + (size_t)g * 16 + l15e;
    *reinterpret_cast<ushort8*>(ef16r + (chunk << 3)) = o;
  } else if (bid < 896) {
    // ---- embT transpose role ----
    float (*tile)[33] = reinterpret_cast<float (*)[33]>(smem);
    int tb = bid - 640;
    int be = tb & 31, bc = tb >> 5;
    int tx = t & 31, ty = t >> 5;
#pragma unroll
    for (int i = 0; i < 4; ++i)
      tile[ty + 8 * i][tx] = emb[(size_t)(be * 32 + ty + 8 * i) * 256 + bc * 32 + tx];
    __syncthreads();
#pragma unroll
    for (int i = 0; i < 4; ++i)
      embT[(size_t)(bc * 32 + ty + 8 * i) * 1024 + be * 32 + tx] = tile[tx][ty + 8 * i];
  } else {
    int n = (bid - 896) * 256 + t;
    enorm[n] = np_sumsq_256_s1(emb + (size_t)n * CDIM);
  }
}

// ---------------------------------------------------------------------------
// Swapped-operand tiled argmin, v11 = r13 math with 4x fatter blocks:
//  * grid 512 (was 2048): block = 128 n x 512 e (4 e-tiles looped).
//    r7/r8 regression showed ~78us per-launch fixed cost independent of
//    K-work; 4x fewer blocks amortizes the per-block prologue/epilogue.
//  * XCD-bijective: xcd=bid&7, 2 e-halves x 32 n-panels per XCD; z panel
//    fragments L1/L2-hot across the 4 e-tiles; FETCH stays ~21MB.
//  * per-(lane,ei,rg,nj) math identical to r13 (passed, absmax 3.8e-6);
//    running top-2 carried across e-tiles, ascending-e scan preserved,
//    one butterfly + cross-wr merge tail per block.
__global__ __launch_bounds__(256, 4) void argmin_tile(
    const unsigned short* __restrict__ zf16r, const unsigned short* __restrict__ ef16r,
    const float* __restrict__ znorm, const float* __restrict__ enorm,
    float* __restrict__ pbd, int* __restrict__ pbi, float* __restrict__ pb2) {
  __shared__ float sdd[128][2];
  __shared__ float sd2[128][2];
  __shared__ int   sdi[128][2];

  const int tid = threadIdx.x;
  const int lane = tid & 63, w = tid >> 6;
  const int wr = w >> 1, wc = w & 1;     // wr = e-half of tile, wc = n-half
  const int l15 = lane & 15, g = lane >> 4;

  // 512 blocks: xcd = bid&7; bit3 = e-half nb2; bits4+ = n-panel (0..31)
  const int bid = blockIdx.x;
  const int nb2 = (bid >> 3) & 1;
  const int mb = (bid & 7) * 32 + (bid >> 4);
  const int n0 = mb * 128;

  // z-fragments as B operand (fixed across e-tiles)
  const unsigned short* bP0 = zf16r + (size_t)(mb * 2 + wc) * 16384 + lane * 8;

  const int n0w = n0 + wc * 64;
  float zn[4];
#pragma unroll
  for (int nj = 0; nj < 4; ++nj) zn[nj] = znorm[n0w + nj * 16 + l15];

  float bd[4], b2[4]; int bi[4];
#pragma unroll
  for (int nj = 0; nj < 4; ++nj) { bd[nj] = 3.4e38f; b2[nj] = 3.4e38f; bi[nj] = 0; }

  const f32x4 z4 = {0.f, 0.f, 0.f, 0.f};
#pragma unroll 1
  for (int et = 0; et < 4; ++et) {
    // E slab index: e/64 = nb2*8 + et*2 + wr
    const unsigned short* aP = ef16r + (size_t)(nb2 * 8 + et * 2 + wr) * 16384 + lane * 8;
    const unsigned short* bP = bP0;

    f32x4 acc[4][4];
#pragma unroll
    for (int ei = 0; ei < 4; ++ei)
#pragma unroll
      for (int nj = 0; nj < 4; ++nj) acc[ei][nj] = z4;

#pragma unroll 1
    for (int kc = 0; kc < 8; ++kc) {
      f16x8 af[4], bv[4];
#pragma unroll
      for (int ei = 0; ei < 4; ++ei)
        af[ei] = *reinterpret_cast<const f16x8*>(aP + ei * 512);
#pragma unroll
      for (int nj = 0; nj < 4; ++nj)
        bv[nj] = *reinterpret_cast<const f16x8*>(bP + nj * 512);
      aP += 2048; bP += 2048;
#pragma unroll
      for (int ei = 0; ei < 4; ++ei)
#pragma unroll
        for (int nj = 0; nj < 4; ++nj)
          acc[ei][nj] = __builtin_amdgcn_mfma_f32_16x16x32_f16(af[ei], bv[nj],
                                                               acc[ei][nj], 0, 0, 0);
    }

    // in-lane ascending-e top-2 scan (pure VALU), running across e-tiles
    const int e0w = nb2 * 512 + et * 128 + wr * 64;
#pragma unroll
    for (int ei = 0; ei < 4; ++ei)
#pragma unroll
      for (int rg = 0; rg < 4; ++rg) {
        int e = e0w + ei * 16 + g * 4 + rg;
        float en = enorm[e];
#pragma unroll
        for (int nj = 0; nj < 4; ++nj) {
          float d = fmaf(NEG2_SCALE, acc[ei][nj][rg], __fadd_rn(zn[nj], en));
          if (d < bd[nj]) {
            b2[nj] = bd[nj]; bd[nj] = d; bi[nj] = e;
          } else if (d < b2[nj]) {
            b2[nj] = d;
          }
        }
      }
  }

  // cross-g butterfly (lanes {l15+16g} share n; disjoint e-subsets)
#pragma unroll
  for (int nj = 0; nj < 4; ++nj) {
#pragma unroll
    for (int m = 16; m <= 32; m <<= 1) {
      float od = __shfl_xor(bd[nj], m, 64);
      int   oi = __shfl_xor(bi[nj], m, 64);
      float o2 = __shfl_xor(b2[nj], m, 64);
      float hi = fmaxf(bd[nj], od);
      b2[nj] = fminf(fminf(b2[nj], o2), hi);
      if (od < bd[nj] || (od == bd[nj] && oi < bi[nj])) { bd[nj] = od; bi[nj] = oi; }
    }
    if (g == 0) {
      int nl = wc * 64 + nj * 16 + l15;   // block-local n (0..127)
      sdd[nl][wr] = bd[nj];
      sdi[nl][wr] = bi[nj];
      sd2[nl][wr] = b2[nj];
    }
  }
  __syncthreads();

  // cross-wr 2-way merge (e-half subsets), exact first-index tie-break
  if (tid < 128) {
    float d0 = sdd[tid][0], d1 = sdd[tid][1];
    int   i0 = sdi[tid][0], i1 = sdi[tid][1];
    float s0 = sd2[tid][0], s1 = sd2[tid][1];
    float bdf; int bif;
    if (d1 < d0 || (d1 == d0 && i1 < i0)) { bdf = d1; bif = i1; } else { bdf = d0; bif = i0; }
    float b2f = fminf(fminf(s0, s1), fmaxf(d0, d1));
    size_t o = (size_t)(n0 + tid) * 2 + nb2;
    pbd[o] = bdf; pbi[o] = bif; pb2[o] = b2f;
  }
}

// ---------------------------------------------------------------------------
// merge 2 per-block top-2 candidates per row + block loss partial sum
__global__ __launch_bounds__(256) void merge_kernel(
    const float* __restrict__ pbd, const int* __restrict__ pbi,
    const float* __restrict__ pb2,
    int* __restrict__ idx_out, float* __restrict__ loss_blk,
    int* __restrict__ flag_cnt, int* __restrict__ flag_list) {
  __shared__ float red[256];
  const int t = threadIdx.x;
  int n = blockIdx.x * 256 + t;
  float d0 = pbd[(size_t)n * 2], d1 = pbd[(size_t)n * 2 + 1];
  int   i0 = pbi[(size_t)n * 2], i1 = pbi[(size_t)n * 2 + 1];
  float s0 = pb2[(size_t)n * 2], s1 = pb2[(size_t)n * 2 + 1];
  float bd; int bi;
  if (d1 < d0 || (d1 == d0 && i1 < i0)) { bd = d1; bi = i1; } else { bd = d0; bi = i0; }
  float b2 = fminf(fminf(s0, s1), fmaxf(d0, d1));
  idx_out[n] = bi;
  if (b2 - bd < THETA) {
    int p = atomicAdd(flag_cnt, 1);
    flag_list[p] = n;
  }
  // block loss partial (fast-path bd; flagged-row delta < theta -> negligible
  // vs 2% loss tolerance, same semantics as prior rounds)
  red[t] = bd;
  __syncthreads();
  for (int s2 = 128; s2 > 0; s2 >>= 1) {
    if (t < s2) red[t] += red[t + s2];
    __syncthreads();
  }
  if (t == 0) loss_blk[blockIdx.x] = red[0];
}

// ---------------------------------------------------------------------------
// coalesced exact-fp32 repair: 4 flagged rows per block share one embT
// stream; per-row fmaf chain identical to the r1-certified arithmetic.
__global__ __launch_bounds__(256) void repair_kernel(
    const float* __restrict__ z, const float* __restrict__ embT,
    const float* __restrict__ znorm, const float* __restrict__ enorm,
    const int* __restrict__ flag_cnt, const int* __restrict__ flag_list,
    int* __restrict__ idx_out) {
  __shared__ float zrow[4][256];
  __shared__ float rd[256];
  __shared__ int   ri[256];
  const int t = threadIdx.x;
  const int cnt = flag_cnt[0] < NROWS ? flag_cnt[0] : NROWS;
  const int nquad = (cnt + 3) >> 2;
  const float4* embT4 = reinterpret_cast<const float4*>(embT);
  for (int j = blockIdx.x; j < nquad; j += gridDim.x) {
    int nr[4];
    __syncthreads();
#pragma unroll
    for (int r = 0; r < 4; ++r) {
      int jr = j * 4 + r;
      nr[r] = flag_list[jr < cnt ? jr : cnt - 1];
      zrow[r][t] = z[(size_t)(nr[r] >> 10) * ZB_STRIDE + (size_t)t * 1024 + (nr[r] & 1023)];
    }
    __syncthreads();
    float4 dot[4] = {{0.f,0.f,0.f,0.f},{0.f,0.f,0.f,0.f},{0.f,0.f,0.f,0.f},{0.f,0.f,0.f,0.f}};
    for (int k = 0; k < 256; ++k) {
      float4 v = embT4[k * 256 + t];
#pragma unroll
      for (int r = 0; r < 4; ++r) {
        float s = zrow[r][k];
        dot[r].x = fmaf(s, v.x, dot[r].x);
        dot[r].y = fmaf(s, v.y, dot[r].y);
        dot[r].z = fmaf(s, v.z, dot[r].z);
        dot[r].w = fmaf(s, v.w, dot[r].w);
      }
    }
#pragma unroll 1
    for (int r = 0; r < 4; ++r) {
      const float zn = znorm[nr[r]];
      float bd = 3.4e38f; int bi = 0;
      const float dv[4] = {dot[r].x, dot[r].y, dot[r].z, dot[r].w};
#pragma unroll
      for (int q = 0; q < 4; ++q) {
        int e = t * 4 + q;
        float d = __fsub_rn(__fadd_rn(zn, enorm[e]), __fmul_rn(2.0f, dv[q]));
        if (d < bd) { bd = d; bi = e; }
      }
      rd[t] = bd; ri[t] = bi;
      __syncthreads();
      for (int s2 = 128; s2 > 0; s2 >>= 1) {
        if (t < s2) {
          float od = rd[t + s2]; int oi = ri[t + s2];
          if (od < rd[t] || (od == rd[t] && oi < ri[t])) { rd[t] = od; ri[t] = oi; }
        }
        __syncthreads();
      }
      if (t == 0) idx_out[nr[r]] = ri[0];
      __syncthreads();
    }
  }
}

// ---------------------------------------------------------------------------
// Fused outputs: all 2048 blocks stream the one-hot; blocks [0,1024) also
// gather z_q via LDS-staged emb rows (coalesced float4 loads AND stores);
// blocks [1024,1152) write idx-as-float + histogram.
__global__ __launch_bounds__(256) void outputs_kernel(const int* __restrict__ idx,
                                                      const float* __restrict__ emb,
                                                      float* __restrict__ out_enc,
                                                      float* __restrict__ out_idxf,
                                                      int* __restrict__ hist,
                                                      float* __restrict__ zq_out) {
  const int t = threadIdx.x;
  for (int i = blockIdx.x * 256 + t; i < NROWS * 256; i += 2048 * 256) {
    int n = i >> 8, j4 = i & 255;
    int e = idx[n];
    float4 v = {0.f, 0.f, 0.f, 0.f};
    if ((e >> 2) == j4) ((float*)&v)[e & 3] = 1.0f;
    reinterpret_cast<float4*>(out_enc)[i] = v;
  }
  if (blockIdx.x < 1024) {
    __shared__ int   sidx[32];
    __shared__ float erow[32][257];
    int b = blockIdx.x >> 5, h = blockIdx.x & 31;
    if (t < 32) sidx[t] = idx[b * 1024 + h * 32 + t];
    __syncthreads();
    const float4* emb4 = reinterpret_cast<const float4*>(emb);
    int rj = t >> 3, v0 = t & 7;
    int er = sidx[rj];
#pragma unroll
    for (int u = 0; u < 8; ++u) {
      int f4 = v0 + 8 * u;
      float4 vv = emb4[(size_t)er * 64 + f4];
      erow[rj][f4 * 4 + 0] = vv.x;
      erow[rj][f4 * 4 + 1] = vv.y;
      erow[rj][f4 * 4 + 2] = vv.z;
      erow[rj][f4 * 4 + 3] = vv.w;
    }
    __syncthreads();
    int w4 = t & 7, cs = t >> 3;
    float4* zq4 = reinterpret_cast<float4*>(zq_out + (size_t)b * ZB_STRIDE + h * 32);
#pragma unroll
    for (int u = 0; u < 8; ++u) {
      int c = cs + 32 * u;
      float4 o = {erow[w4 * 4 + 0][c], erow[w4 * 4 + 1][c],
                  erow[w4 * 4 + 2][c], erow[w4 * 4 + 3][c]};
      zq4[(size_t)c * 256 + w4] = o;
    }
  } else if (blockIdx.x < 1152) {
    int n = (blockIdx.x - 1024) * 256 + t;
    int e = idx[n];
    out_idxf[n] = (float)e;
    atomicAdd(&hist[e], 1);
  }
}

__global__ __launch_bounds__(256) void finalize_kernel(const float* __restrict__ loss_blk,
                                                       const int* __restrict__ hist,
                                                       float* __restrict__ out_loss,
                                                       float* __restrict__ out_perp) {
  __shared__ float red[256];
  int t = threadIdx.x;
  red[t] = (t < 128) ? loss_blk[t] : 0.f;
  __syncthreads();
  for (int s2 = 128; s2 > 0; s2 >>= 1) {
    if (t < s2) red[t] += red[t + s2];
    __syncthreads();
  }
  if (t == 0) out_loss[0] = 1.25f * (red[0] / 8388608.0f);
  __syncthreads();
  float hs = 0.f;
  for (int i = t; i < 1024; i += 256) {
    float em = (float)hist[i] / 32768.0f;
    hs += em * logf(em + 1e-10f);
  }
  red[t] = hs;
  __syncthreads();
  for (int s2 = 128; s2 > 0; s2 >>= 1) {
    if (t < s2) red[t] += red[t + s2];
    __syncthreads();
  }
  if (t == 0) out_perp[0] = expf(-red[0]);
}

// ---------------------------------------------------------------------------
extern "C" void kernel_launch(void* const* d_in, const int* in_sizes, int n_in,
                              void* d_out, int out_size, void* d_ws, size_t ws_size,
                              hipStream_t stream) {
  const float* z   = (const float*)d_in[0];
  const float* emb = (const float*)d_in[1];
  float* out = (float*)d_out;

  float* out_zq   = out + ZQ_OFF;
  float* out_loss = out + LOSS_OFF;
  float* out_perp = out + PERP_OFF;
  float* out_enc  = out + ENC_OFF;
  float* out_idxf = out + IDX_OFF;

  // workspace (small)
  int*   idx       = (int*)d_ws;                   // 32768
  int*   hist      = idx + NROWS;                  // 1024
  int*   flag_cnt  = hist + NE;                    // 4 (1 used)
  int*   flag_list = flag_cnt + 4;                 // 32768
  float* loss_blk  = (float*)(flag_list + NROWS);  // 128
  float* znorm     = loss_blk + 128;               // 32768
  float* enorm     = znorm + NROWS;                // 1024

  // staging buffers carved from the one-hot output region (overwritten later)
  unsigned short* zf16r = (unsigned short*)(out_enc + 2);    // 8388608 u16 (16B-aligned)
  unsigned short* ef16r = zf16r + (size_t)NROWS * CDIM;      // 262144 u16
  float*          embT  = (float*)(ef16r + (size_t)NE * CDIM);// 262144 f32
  float*          pbd   = embT + 262144;                     // 65536 f32
  int*            pbi   = (int*)(pbd + 65536);               // 65536 i32
  float*          pb2   = (float*)(pbi + 65536);             // 65536 f32

  // hist (NE ints) and flag_cnt (adjacent) in one memset
  hipMemsetAsync(hist, 0, (NE + 1) * sizeof(int), stream);

  convert_all<<<900, 256, 0, stream>>>(z, emb, zf16r, ef16r, embT, znorm, enorm);
  argmin_tile<<<512, 256, 0, stream>>>(zf16r, ef16r, znorm, enorm, pbd, pbi, pb2);
  merge_kernel<<<NROWS / 256, 256, 0, stream>>>(pbd, pbi, pb2, idx, loss_blk, flag_cnt, flag_list);
  repair_kernel<<<256, 256, 0, stream>>>(z, embT, znorm, enorm, flag_cnt, flag_list, idx);
  outputs_kernel<<<2048, 256, 0, stream>>>(idx, emb, out_enc, out_idxf, hist, out_zq);
  finalize_kernel<<<1, 256, 0, stream>>>(loss_blk, hist, out_loss, out_perp);
}

// Round 15
// 153.386 us; speedup vs baseline: 1.5042x; 1.0262x over previous
//
#include <hip/hip_runtime.h>
#include <math.h>

#define NROWS 32768
#define NE    1024
#define CDIM  256
#define ZB_STRIDE 262144

#define ZQ_OFF   0
#define LOSS_OFF 8388608
#define PERP_OFF 8388609
#define ENC_OFF  8388610
#define IDX_OFF  41943042

#define THETA 1.0e-4f
// e scaled by 2^12 before fp16 conversion; -2*dot = -2^-11 * acc
#define NEG2_SCALE (-0.00048828125f)

typedef _Float16 f16x8 __attribute__((ext_vector_type(8)));
typedef __attribute__((ext_vector_type(4))) float f32x4;
typedef __attribute__((ext_vector_type(8))) unsigned short ushort8;

// RNE float -> fp16 bits
__device__ __forceinline__ unsigned short f2h(float x) {
  _Float16 h = (_Float16)x;
  unsigned short u;
  __builtin_memcpy(&u, &h, 2);
  return u;
}

// ---------------------------------------------------------------------------
// numpy-pairwise-exact sum of squares (stride 1)
__device__ __forceinline__ float np_sumsq_256_s1(const float* __restrict__ base) {
  float tot[2];
#pragma unroll
  for (int hh = 0; hh < 2; ++hh) {
    float r[8];
#pragma unroll
    for (int j = 0; j < 8; ++j) {
      float x = base[hh * 128 + j];
      r[j] = __fmul_rn(x, x);
    }
    for (int i = 8; i < 128; i += 8) {
#pragma unroll
      for (int j = 0; j < 8; ++j) {
        float x = base[hh * 128 + i + j];
        r[j] = __fadd_rn(r[j], __fmul_rn(x, x));
      }
    }
    tot[hh] = __fadd_rn(__fadd_rn(__fadd_rn(r[0], r[1]), __fadd_rn(r[2], r[3])),
                        __fadd_rn(__fadd_rn(r[4], r[5]), __fadd_rn(r[6], r[7])));
  }
  return __fadd_rn(tot[0], tot[1]);
}

// ---------------------------------------------------------------------------
// Fused convert: blocks [0,512) = convert_z role (r4-certified norm tree +
// fragment-order fp16 write); [512,640) = convert_e fragment role;
// [640,896) = embT transpose; [896,900) = enorm.
__global__ __launch_bounds__(256) void convert_all(const float* __restrict__ z,
                                                   const float* __restrict__ emb,
                                                   unsigned short* __restrict__ zf16r,
                                                   unsigned short* __restrict__ ef16r,
                                                   float* __restrict__ embT,
                                                   float* __restrict__ znorm,
                                                   float* __restrict__ enorm) {
  __shared__ __align__(16) char smem[38144];
  const int bid = blockIdx.x;
  const int t = threadIdx.x;

  if (bid < 512) {
    unsigned short (*T16)[266] = reinterpret_cast<unsigned short (*)[266]>(smem);
    float (*accsF)[8][16][4] = reinterpret_cast<float (*)[8][16][4]>(smem + 34048);
    const int b = bid >> 4, hwt = bid & 15;
    const int hw0 = hwt * 64;
    const int hw4 = t & 15;
    const int jj = (t >> 4) & 7;
    const int hh = t >> 7;
    const float* zb = z + (size_t)b * ZB_STRIDE + hw0 + hw4 * 4;

    float rr[4];
#pragma unroll
    for (int i = 0; i < 16; ++i) {
      int c = hh * 128 + jj + 8 * i;
      float4 v = *reinterpret_cast<const float4*>(zb + (size_t)c * 1024);
      const float xv[4] = {v.x, v.y, v.z, v.w};
#pragma unroll
      for (int q = 0; q < 4; ++q) {
        float p = __fmul_rn(xv[q], xv[q]);
        rr[q] = (i == 0) ? p : __fadd_rn(rr[q], p);
        T16[hw4 * 4 + q][c] = f2h(xv[q]);
      }
    }
#pragma unroll
    for (int q = 0; q < 4; ++q) accsF[hh][jj][hw4][q] = rr[q];
    __syncthreads();

    if (t < 64) {
      const int h4 = t >> 2, cq = t & 3;
      float tot[2];
#pragma unroll
      for (int half = 0; half < 2; ++half) {
        float r[8];
#pragma unroll
        for (int j = 0; j < 8; ++j) r[j] = accsF[half][j][h4][cq];
        tot[half] = __fadd_rn(__fadd_rn(__fadd_rn(r[0], r[1]), __fadd_rn(r[2], r[3])),
                              __fadd_rn(__fadd_rn(r[4], r[5]), __fadd_rn(r[6], r[7])));
      }
      znorm[b * 1024 + hw0 + t] = __fadd_rn(tot[0], tot[1]);
    }

    const int pw = b * 16 + hwt;
    const int panel = pw >> 1, wrh = pw & 1;
    const int l15w = t & 15, gw = (t >> 4) & 3, miw = t >> 6;
    const int rowW = miw * 16 + l15w;
#pragma unroll
    for (int kc = 0; kc < 8; ++kc) {
      ushort8 o;
#pragma unroll
      for (int el = 0; el < 8; ++el) o[el] = T16[rowW][kc * 32 + gw * 8 + el];
      size_t chunk = ((((size_t)panel * 2 + wrh) * 8 + kc) * 4 + miw) * 64 + (size_t)gw * 16 + l15w;
      *reinterpret_cast<ushort8*>(zf16r + (chunk << 3)) = o;
    }
  } else if (bid < 640) {
    int cid = (bid - 512) * 256 + t;
    int e = cid >> 5, cc = cid & 31;
    int kc = cc >> 2, g = cc & 3;
    int c0 = kc * 32 + g * 8;
    ushort8 o;
#pragma unroll
    for (int el = 0; el < 8; ++el) o[el] = f2h(emb[(size_t)e * 256 + c0 + el] * 4096.0f);
    int et = e >> 7, wcb = (e >> 6) & 1, nj = (e >> 4) & 3, l15e = e & 15;
    size_t chunk = ((((size_t)et * 2 + wcb) * 8 + kc) * 4 + nj) * 64 + (size_t)g * 16 + l15e;
    *reinterpret_cast<ushort8*>(ef16r + (chunk << 3)) = o;
  } else if (bid < 896) {
    float (*tile)[33] = reinterpret_cast<float (*)[33]>(smem);
    int tb = bid - 640;
    int be = tb & 31, bc = tb >> 5;
    int tx = t & 31, ty = t >> 5;
#pragma unroll
    for (int i = 0; i < 4; ++i)
      tile[ty + 8 * i][tx] = emb[(size_t)(be * 32 + ty + 8 * i) * 256 + bc * 32 + tx];
    __syncthreads();
#pragma unroll
    for (int i = 0; i < 4; ++i)
      embT[(size_t)(bc * 32 + ty + 8 * i) * 1024 + be * 32 + tx] = tile[tx][ty + 8 * i];
  } else {
    int n = (bid - 896) * 256 + t;
    enorm[n] = np_sumsq_256_s1(emb + (size_t)n * CDIM);
  }
}

// ---------------------------------------------------------------------------
// Swapped-operand argmin, v12 = r14 math, block = 64 n x ALL 1024 e,
// finalized in-kernel (merge_kernel deleted):
//  * grid 512, 256 thr (2 blocks/CU -> 2 waves/SIMD TLP, the r14-proven
//    operating point; grid 256 would drop to 1 wave/SIMD = r5 failure mode).
//  * wave w owns contiguous e-quarter [w*256,(w+1)*256) = 4 slabs ascending;
//    all 4 waves share the block's 16KB z-slab as B (L1-hot).
//  * per-(lane,e,n) d arithmetic, ascending-e top-2 scan, cross-g butterfly
//    identical to r14 (passed, absmax 3.8e-6). Waves are e-ordered ->
//    4-way lexicographic merge preserves exact first-index semantics.
//  * idx/flag/loss-partial written here; pb arrays gone.
__global__ __launch_bounds__(256, 4) void argmin_tile(
    const unsigned short* __restrict__ zf16r, const unsigned short* __restrict__ ef16r,
    const float* __restrict__ znorm, const float* __restrict__ enorm,
    int* __restrict__ idx_out, float* __restrict__ loss_blk,
    int* __restrict__ flag_cnt, int* __restrict__ flag_list) {
  __shared__ float sdd[64][4];
  __shared__ float sd2[64][4];
  __shared__ int   sdi[64][4];

  const int tid = threadIdx.x;
  const int lane = tid & 63, w = tid >> 6;     // w = e-quarter (0..3)
  const int l15 = lane & 15, g = lane >> 4;

  // XCD-bijective: xcd = bid&7; 64 consecutive n-slabs per XCD
  const int bid = blockIdx.x;
  const int mb = (bid & 7) * 64 + (bid >> 3);  // n-slab 0..511
  const int n0 = mb * 64;

  // z-fragments as B operand (same slab for all 4 waves, L1-hot)
  const unsigned short* bP0 = zf16r + (size_t)mb * 16384 + lane * 8;

  float zn[4];
#pragma unroll
  for (int nj = 0; nj < 4; ++nj) zn[nj] = znorm[n0 + nj * 16 + l15];

  float bd[4], b2[4]; int bi[4];
#pragma unroll
  for (int nj = 0; nj < 4; ++nj) { bd[nj] = 3.4e38f; b2[nj] = 3.4e38f; bi[nj] = 0; }

  const f32x4 z4 = {0.f, 0.f, 0.f, 0.f};
#pragma unroll 1
  for (int et = 0; et < 4; ++et) {
    // e-slab index: e/64 = w*4 + et
    const unsigned short* aP = ef16r + (size_t)(w * 4 + et) * 16384 + lane * 8;
    const unsigned short* bP = bP0;

    f32x4 acc[4][4];
#pragma unroll
    for (int ei = 0; ei < 4; ++ei)
#pragma unroll
      for (int nj = 0; nj < 4; ++nj) acc[ei][nj] = z4;

#pragma unroll 1
    for (int kc = 0; kc < 8; ++kc) {
      f16x8 af[4], bv[4];
#pragma unroll
      for (int ei = 0; ei < 4; ++ei)
        af[ei] = *reinterpret_cast<const f16x8*>(aP + ei * 512);
#pragma unroll
      for (int nj = 0; nj < 4; ++nj)
        bv[nj] = *reinterpret_cast<const f16x8*>(bP + nj * 512);
      aP += 2048; bP += 2048;
#pragma unroll
      for (int ei = 0; ei < 4; ++ei)
#pragma unroll
        for (int nj = 0; nj < 4; ++nj)
          acc[ei][nj] = __builtin_amdgcn_mfma_f32_16x16x32_f16(af[ei], bv[nj],
                                                               acc[ei][nj], 0, 0, 0);
    }

    // in-lane ascending-e top-2 scan (pure VALU), running across slabs
    const int e0w = (w * 4 + et) * 64;
#pragma unroll
    for (int ei = 0; ei < 4; ++ei)
#pragma unroll
      for (int rg = 0; rg < 4; ++rg) {
        int e = e0w + ei * 16 + g * 4 + rg;
        float en = enorm[e];
#pragma unroll
        for (int nj = 0; nj < 4; ++nj) {
          float d = fmaf(NEG2_SCALE, acc[ei][nj][rg], __fadd_rn(zn[nj], en));
          if (d < bd[nj]) {
            b2[nj] = bd[nj]; bd[nj] = d; bi[nj] = e;
          } else if (d < b2[nj]) {
            b2[nj] = d;
          }
        }
      }
  }

  // cross-g butterfly (lanes {l15+16g} share n; disjoint e-subsets)
#pragma unroll
  for (int nj = 0; nj < 4; ++nj) {
#pragma unroll
    for (int m = 16; m <= 32; m <<= 1) {
      float od = __shfl_xor(bd[nj], m, 64);
      int   oi = __shfl_xor(bi[nj], m, 64);
      float o2 = __shfl_xor(b2[nj], m, 64);
      float hi = fmaxf(bd[nj], od);
      b2[nj] = fminf(fminf(b2[nj], o2), hi);
      if (od < bd[nj] || (od == bd[nj] && oi < bi[nj])) { bd[nj] = od; bi[nj] = oi; }
    }
    if (g == 0) {
      int nl = nj * 16 + l15;            // block-local n (0..63)
      sdd[nl][w] = bd[nj];
      sdi[nl][w] = bi[nj];
      sd2[nl][w] = b2[nj];
    }
  }
  __syncthreads();

  // 4-way cross-wave merge (waves e-ordered), exact first-index tie-break;
  // then in-wave loss reduction (tid<64 is exactly wave 0)
  if (tid < 64) {
    float bdf = 3.4e38f; int bif = 0x7FFFFFFF; int bw = -1;
#pragma unroll
    for (int ww = 0; ww < 4; ++ww) {
      float d = sdd[tid][ww];
      int   i = sdi[tid][ww];
      if (d < bdf || (d == bdf && i < bif)) { bdf = d; bif = i; bw = ww; }
    }
    float b2f = 3.4e38f;
#pragma unroll
    for (int ww = 0; ww < 4; ++ww) {
      float v = (ww == bw) ? sd2[tid][ww] : sdd[tid][ww];
      b2f = fminf(b2f, v);
    }
    int n = n0 + tid;
    idx_out[n] = bif;
    if (b2f - bdf < THETA) {
      int p = atomicAdd(flag_cnt, 1);
      flag_list[p] = n;
    }
    // loss partial: wave-local butterfly sum of the 64 bd values
    float s = bdf;
#pragma unroll
    for (int m = 1; m <= 32; m <<= 1) s += __shfl_xor(s, m, 64);
    if (tid == 0) loss_blk[bid] = s;
  }
}

// ---------------------------------------------------------------------------
// coalesced exact-fp32 repair: 4 flagged rows per block share one embT
// stream; per-row fmaf chain identical to the r1-certified arithmetic.
__global__ __launch_bounds__(256) void repair_kernel(
    const float* __restrict__ z, const float* __restrict__ embT,
    const float* __restrict__ znorm, const float* __restrict__ enorm,
    const int* __restrict__ flag_cnt, const int* __restrict__ flag_list,
    int* __restrict__ idx_out) {
  __shared__ float zrow[4][256];
  __shared__ float rd[256];
  __shared__ int   ri[256];
  const int t = threadIdx.x;
  const int cnt = flag_cnt[0] < NROWS ? flag_cnt[0] : NROWS;
  const int nquad = (cnt + 3) >> 2;
  const float4* embT4 = reinterpret_cast<const float4*>(embT);
  for (int j = blockIdx.x; j < nquad; j += gridDim.x) {
    int nr[4];
    __syncthreads();
#pragma unroll
    for (int r = 0; r < 4; ++r) {
      int jr = j * 4 + r;
      nr[r] = flag_list[jr < cnt ? jr : cnt - 1];
      zrow[r][t] = z[(size_t)(nr[r] >> 10) * ZB_STRIDE + (size_t)t * 1024 + (nr[r] & 1023)];
    }
    __syncthreads();
    float4 dot[4] = {{0.f,0.f,0.f,0.f},{0.f,0.f,0.f,0.f},{0.f,0.f,0.f,0.f},{0.f,0.f,0.f,0.f}};
    for (int k = 0; k < 256; ++k) {
      float4 v = embT4[k * 256 + t];
#pragma unroll
      for (int r = 0; r < 4; ++r) {
        float s = zrow[r][k];
        dot[r].x = fmaf(s, v.x, dot[r].x);
        dot[r].y = fmaf(s, v.y, dot[r].y);
        dot[r].z = fmaf(s, v.z, dot[r].z);
        dot[r].w = fmaf(s, v.w, dot[r].w);
      }
    }
#pragma unroll 1
    for (int r = 0; r < 4; ++r) {
      const float zn = znorm[nr[r]];
      float bd = 3.4e38f; int bi = 0;
      const float dv[4] = {dot[r].x, dot[r].y, dot[r].z, dot[r].w};
#pragma unroll
      for (int q = 0; q < 4; ++q) {
        int e = t * 4 + q;
        float d = __fsub_rn(__fadd_rn(zn, enorm[e]), __fmul_rn(2.0f, dv[q]));
        if (d < bd) { bd = d; bi = e; }
      }
      rd[t] = bd; ri[t] = bi;
      __syncthreads();
      for (int s2 = 128; s2 > 0; s2 >>= 1) {
        if (t < s2) {
          float od = rd[t + s2]; int oi = ri[t + s2];
          if (od < rd[t] || (od == rd[t] && oi < ri[t])) { rd[t] = od; ri[t] = oi; }
        }
        __syncthreads();
      }
      if (t == 0) idx_out[nr[r]] = ri[0];
      __syncthreads();
    }
  }
}

// ---------------------------------------------------------------------------
// Fused outputs: all 2048 blocks stream the one-hot; blocks [0,1024) also
// gather z_q via LDS-staged emb rows (coalesced float4 loads AND stores);
// blocks [1024,1152) write idx-as-float + histogram.
__global__ __launch_bounds__(256) void outputs_kernel(const int* __restrict__ idx,
                                                      const float* __restrict__ emb,
                                                      float* __restrict__ out_enc,
                                                      float* __restrict__ out_idxf,
                                                      int* __restrict__ hist,
                                                      float* __restrict__ zq_out) {
  const int t = threadIdx.x;
  for (int i = blockIdx.x * 256 + t; i < NROWS * 256; i += 2048 * 256) {
    int n = i >> 8, j4 = i & 255;
    int e = idx[n];
    float4 v = {0.f, 0.f, 0.f, 0.f};
    if ((e >> 2) == j4) ((float*)&v)[e & 3] = 1.0f;
    reinterpret_cast<float4*>(out_enc)[i] = v;
  }
  if (blockIdx.x < 1024) {
    __shared__ int   sidx[32];
    __shared__ float erow[32][257];
    int b = blockIdx.x >> 5, h = blockIdx.x & 31;
    if (t < 32) sidx[t] = idx[b * 1024 + h * 32 + t];
    __syncthreads();
    const float4* emb4 = reinterpret_cast<const float4*>(emb);
    int rj = t >> 3, v0 = t & 7;
    int er = sidx[rj];
#pragma unroll
    for (int u = 0; u < 8; ++u) {
      int f4 = v0 + 8 * u;
      float4 vv = emb4[(size_t)er * 64 + f4];
      erow[rj][f4 * 4 + 0] = vv.x;
      erow[rj][f4 * 4 + 1] = vv.y;
      erow[rj][f4 * 4 + 2] = vv.z;
      erow[rj][f4 * 4 + 3] = vv.w;
    }
    __syncthreads();
    int w4 = t & 7, cs = t >> 3;
    float4* zq4 = reinterpret_cast<float4*>(zq_out + (size_t)b * ZB_STRIDE + h * 32);
#pragma unroll
    for (int u = 0; u < 8; ++u) {
      int c = cs + 32 * u;
      float4 o = {erow[w4 * 4 + 0][c], erow[w4 * 4 + 1][c],
                  erow[w4 * 4 + 2][c], erow[w4 * 4 + 3][c]};
      zq4[(size_t)c * 256 + w4] = o;
    }
  } else if (blockIdx.x < 1152) {
    int n = (blockIdx.x - 1024) * 256 + t;
    int e = idx[n];
    out_idxf[n] = (float)e;
    atomicAdd(&hist[e], 1);
  }
}

__global__ __launch_bounds__(256) void finalize_kernel(const float* __restrict__ loss_blk,
                                                       const int* __restrict__ hist,
                                                       float* __restrict__ out_loss,
                                                       float* __restrict__ out_perp) {
  __shared__ float red[256];
  int t = threadIdx.x;
  red[t] = loss_blk[t] + loss_blk[t + 256];
  __syncthreads();
  for (int s2 = 128; s2 > 0; s2 >>= 1) {
    if (t < s2) red[t] += red[t + s2];
    __syncthreads();
  }
  if (t == 0) out_loss[0] = 1.25f * (red[0] / 8388608.0f);
  __syncthreads();
  float hs = 0.f;
  for (int i = t; i < 1024; i += 256) {
    float em = (float)hist[i] / 32768.0f;
    hs += em * logf(em + 1e-10f);
  }
  red[t] = hs;
  __syncthreads();
  for (int s2 = 128; s2 > 0; s2 >>= 1) {
    if (t < s2) red[t] += red[t + s2];
    __syncthreads();
  }
  if (t == 0) out_perp[0] = expf(-red[0]);
}

// ---------------------------------------------------------------------------
extern "C" void kernel_launch(void* const* d_in, const int* in_sizes, int n_in,
                              void* d_out, int out_size, void* d_ws, size_t ws_size,
                              hipStream_t stream) {
  const float* z   = (const float*)d_in[0];
  const float* emb = (const float*)d_in[1];
  float* out = (float*)d_out;

  float* out_zq   = out + ZQ_OFF;
  float* out_loss = out + LOSS_OFF;
  float* out_perp = out + PERP_OFF;
  float* out_enc  = out + ENC_OFF;
  float* out_idxf = out + IDX_OFF;

  // workspace (small)
  int*   idx       = (int*)d_ws;                   // 32768
  int*   hist      = idx + NROWS;                  // 1024
  int*   flag_cnt  = hist + NE;                    // 4 (1 used)
  int*   flag_list = flag_cnt + 4;                 // 32768
  float* loss_blk  = (float*)(flag_list + NROWS);  // 512
  float* znorm     = loss_blk + 512;               // 32768
  float* enorm     = znorm + NROWS;                // 1024

  // staging buffers carved from the one-hot output region (overwritten later)
  unsigned short* zf16r = (unsigned short*)(out_enc + 2);    // 8388608 u16 (16B-aligned)
  unsigned short* ef16r = zf16r + (size_t)NROWS * CDIM;      // 262144 u16
  float*          embT  = (float*)(ef16r + (size_t)NE * CDIM);// 262144 f32

  // hist (NE ints) and flag_cnt (adjacent) in one memset
  hipMemsetAsync(hist, 0, (NE + 1) * sizeof(int), stream);

  convert_all<<<900, 256, 0, stream>>>(z, emb, zf16r, ef16r, embT, znorm, enorm);
  argmin_tile<<<512, 256, 0, stream>>>(zf16r, ef16r, znorm, enorm,
                                       idx, loss_blk, flag_cnt, flag_list);
  repair_kernel<<<256, 256, 0, stream>>>(z, embT, znorm, enorm, flag_cnt, flag_list, idx);
  outputs_kernel<<<2048, 256, 0, stream>>>(idx, emb, out_enc, out_idxf, hist, out_zq);
  finalize_kernel<<<1, 256, 0, stream>>>(loss_blk, hist, out_loss, out_perp);
}

// Round 16
// 134.847 us; speedup vs baseline: 1.7110x; 1.1375x over previous
//
#include <hip/hip_runtime.h>
#include <math.h>

#define NROWS 32768
#define NE    1024
#define CDIM  256
#define ZB_STRIDE 262144

#define ZQ_OFF   0
#define LOSS_OFF 8388608
#define PERP_OFF 8388609
#define ENC_OFF  8388610
#define IDX_OFF  41943042

#define THETA 1.0e-4f
// e scaled by 2^12 before fp16 conversion; -2*dot = -2^-11 * acc
#define NEG2_SCALE (-0.00048828125f)

typedef _Float16 f16x8 __attribute__((ext_vector_type(8)));
typedef __attribute__((ext_vector_type(4))) float f32x4;
typedef __attribute__((ext_vector_type(8))) unsigned short ushort8;

// RNE float -> fp16 bits
__device__ __forceinline__ unsigned short f2h(float x) {
  _Float16 h = (_Float16)x;
  unsigned short u;
  __builtin_memcpy(&u, &h, 2);
  return u;
}

// ---------------------------------------------------------------------------
// numpy-pairwise-exact sum of squares (stride 1)
__device__ __forceinline__ float np_sumsq_256_s1(const float* __restrict__ base) {
  float tot[2];
#pragma unroll
  for (int hh = 0; hh < 2; ++hh) {
    float r[8];
#pragma unroll
    for (int j = 0; j < 8; ++j) {
      float x = base[hh * 128 + j];
      r[j] = __fmul_rn(x, x);
    }
    for (int i = 8; i < 128; i += 8) {
#pragma unroll
      for (int j = 0; j < 8; ++j) {
        float x = base[hh * 128 + i + j];
        r[j] = __fadd_rn(r[j], __fmul_rn(x, x));
      }
    }
    tot[hh] = __fadd_rn(__fadd_rn(__fadd_rn(r[0], r[1]), __fadd_rn(r[2], r[3])),
                        __fadd_rn(__fadd_rn(r[4], r[5]), __fadd_rn(r[6], r[7])));
  }
  return __fadd_rn(tot[0], tot[1]);
}

// ---------------------------------------------------------------------------
// E prep (role-split, bodies identical to r15's convert_all e-roles):
// blocks [0,128): fp32 -> fp16*2^12 in MFMA-fragment order
// blocks [128,384): emb -> embT fp32 transpose (for repair)
// blocks [384,388): numpy-exact enorm
__global__ __launch_bounds__(256) void prep_e(const float* __restrict__ emb,
                                              unsigned short* __restrict__ ef16r,
                                              float* __restrict__ embT,
                                              float* __restrict__ enorm) {
  const int bid = blockIdx.x;
  const int t = threadIdx.x;
  if (bid < 128) {
    int cid = bid * 256 + t;             // 0..32767
    int e = cid >> 5, cc = cid & 31;
    int kc = cc >> 2, g = cc & 3;
    int c0 = kc * 32 + g * 8;
    ushort8 o;
#pragma unroll
    for (int el = 0; el < 8; ++el) o[el] = f2h(emb[(size_t)e * 256 + c0 + el] * 4096.0f);
    int et = e >> 7, wcb = (e >> 6) & 1, nj = (e >> 4) & 3, l15e = e & 15;
    size_t chunk = ((((size_t)et * 2 + wcb) * 8 + kc) * 4 + nj) * 64 + (size_t)g * 16 + l15e;
    *reinterpret_cast<ushort8*>(ef16r + (chunk << 3)) = o;
  } else if (bid < 384) {
    __shared__ float tile[32][33];
    int tb = bid - 128;
    int be = tb & 31, bc = tb >> 5;
    int tx = t & 31, ty = t >> 5;
#pragma unroll
    for (int i = 0; i < 4; ++i)
      tile[ty + 8 * i][tx] = emb[(size_t)(be * 32 + ty + 8 * i) * 256 + bc * 32 + tx];
    __syncthreads();
#pragma unroll
    for (int i = 0; i < 4; ++i)
      embT[(size_t)(bc * 32 + ty + 8 * i) * 1024 + be * 32 + tx] = tile[tx][ty + 8 * i];
  } else {
    int n = (bid - 384) * 256 + t;
    enorm[n] = np_sumsq_256_s1(emb + (size_t)n * CDIM);
  }
}

// ---------------------------------------------------------------------------
// Fused convert-z + swapped-operand argmin, v13:
//  * block mb converts ITS OWN 64-row z slab (r4-certified norm tree + T16
//    staging, verbatim, t<256 active) -> fragments staged via registers ->
//    Bfrag (32KB) written over T16's LDS space. zf16r (32MB HBM round-trip)
//    and one launch deleted.
//  * Phase B: 512 threads = 8 waves, each owns a contiguous 128-e eighth
//    (2 slabs ascending) -> 4 waves/SIMD TLP (2x r15, the r10/r11 lever);
//    B operand ds_read from LDS (chunk-linear, conflict-free); per-lane
//    fragment bits identical to r15 -> d/theta/tie-break/repair unchanged.
//  * 8-way e-ordered cross-wave merge (r12-proven exact first-index).
__global__ __launch_bounds__(512, 4) void zconv_argmin(
    const float* __restrict__ z, const unsigned short* __restrict__ ef16r,
    const float* __restrict__ enorm, float* __restrict__ znorm,
    int* __restrict__ idx_out, float* __restrict__ loss_blk,
    int* __restrict__ flag_cnt, int* __restrict__ flag_list) {
  __shared__ __align__(16) char smA[34048];        // T16 [64][266] u16, then Bfrag 32KB (union)
  __shared__ float accsF[2][8][16][4];
  __shared__ float znl[64];
  __shared__ float sdd[64][8];
  __shared__ float sd2[64][8];
  __shared__ int   sdi[64][8];

  const int t = threadIdx.x;
  const int bid = blockIdx.x;
  // XCD-bijective: xcd = bid&7; 64 consecutive n-slabs per XCD
  const int mb = (bid & 7) * 64 + (bid >> 3);      // n-slab 0..511
  const int n0 = mb * 64;
  const int b = mb >> 4, hwt = mb & 15;
  const int hw0 = hwt * 64;

  unsigned short (*T16)[266] = reinterpret_cast<unsigned short (*)[266]>(smA);
  unsigned short* Bfrag = reinterpret_cast<unsigned short*>(smA);

  // ---- Phase A1 (t<256): read z slab, squares, T16 fill (r4-certified) ----
  if (t < 256) {
    const int hw4 = t & 15;
    const int jj = (t >> 4) & 7;
    const int hh = t >> 7;
    const float* zb = z + (size_t)b * ZB_STRIDE + hw0 + hw4 * 4;
    float rr[4];
#pragma unroll
    for (int i = 0; i < 16; ++i) {
      int c = hh * 128 + jj + 8 * i;
      float4 v = *reinterpret_cast<const float4*>(zb + (size_t)c * 1024);
      const float xv[4] = {v.x, v.y, v.z, v.w};
#pragma unroll
      for (int q = 0; q < 4; ++q) {
        float p = __fmul_rn(xv[q], xv[q]);
        rr[q] = (i == 0) ? p : __fadd_rn(rr[q], p);
        T16[hw4 * 4 + q][c] = f2h(xv[q]);
      }
    }
#pragma unroll
    for (int q = 0; q < 4; ++q) accsF[hh][jj][hw4][q] = rr[q];
  }
  __syncthreads();

  // ---- Phase A2: norms (t<64) + fragment regs from T16 (t<256) ----
  if (t < 64) {
    const int h4 = t >> 2, cq = t & 3;
    float tot[2];
#pragma unroll
    for (int half = 0; half < 2; ++half) {
      float r[8];
#pragma unroll
      for (int j = 0; j < 8; ++j) r[j] = accsF[half][j][h4][cq];
      tot[half] = __fadd_rn(__fadd_rn(__fadd_rn(r[0], r[1]), __fadd_rn(r[2], r[3])),
                            __fadd_rn(__fadd_rn(r[4], r[5]), __fadd_rn(r[6], r[7])));
    }
    float nr = __fadd_rn(tot[0], tot[1]);
    znl[t] = nr;
    znorm[n0 + t] = nr;
  }
  ushort8 fr[8];
  {
    const int l15w = t & 15, gw = (t >> 4) & 3, miw = (t >> 6) & 3;
    const int rowW = miw * 16 + l15w;
    if (t < 256) {
#pragma unroll
      for (int kc = 0; kc < 8; ++kc)
#pragma unroll
        for (int el = 0; el < 8; ++el) fr[kc][el] = T16[rowW][kc * 32 + gw * 8 + el];
    }
  }
  __syncthreads();

  // ---- Phase A3 (t<256): write fragments to Bfrag (over T16 space) ----
  if (t < 256) {
    const int l15w = t & 15, gw = (t >> 4) & 3, miw = (t >> 6) & 3;
#pragma unroll
    for (int kc = 0; kc < 8; ++kc) {
      int chunk = (kc * 4 + miw) * 64 + gw * 16 + l15w;
      *reinterpret_cast<ushort8*>(Bfrag + chunk * 8) = fr[kc];
    }
  }
  __syncthreads();

  // ---- Phase B: 8-wave argmin over all 1024 e; B from LDS ----
  const int lane = t & 63, w = t >> 6;             // w = e-eighth (0..7)
  const int l15 = lane & 15, g = lane >> 4;

  float zn[4];
#pragma unroll
  for (int nj = 0; nj < 4; ++nj) zn[nj] = znl[nj * 16 + l15];

  float bd[4], b2[4]; int bi[4];
#pragma unroll
  for (int nj = 0; nj < 4; ++nj) { bd[nj] = 3.4e38f; b2[nj] = 3.4e38f; bi[nj] = 0; }

  const f32x4 z4 = {0.f, 0.f, 0.f, 0.f};
#pragma unroll 1
  for (int et = 0; et < 2; ++et) {
    // e-slab index: e/64 = w*2 + et
    const unsigned short* aP = ef16r + (size_t)(w * 2 + et) * 16384 + lane * 8;

    f32x4 acc[4][4];
#pragma unroll
    for (int ei = 0; ei < 4; ++ei)
#pragma unroll
      for (int nj = 0; nj < 4; ++nj) acc[ei][nj] = z4;

#pragma unroll 1
    for (int kc = 0; kc < 8; ++kc) {
      f16x8 af[4], bv[4];
#pragma unroll
      for (int ei = 0; ei < 4; ++ei)
        af[ei] = *reinterpret_cast<const f16x8*>(aP + ei * 512);
#pragma unroll
      for (int nj = 0; nj < 4; ++nj)
        bv[nj] = *reinterpret_cast<const f16x8*>(Bfrag + ((kc * 4 + nj) * 64 + lane) * 8);
      aP += 2048;
#pragma unroll
      for (int ei = 0; ei < 4; ++ei)
#pragma unroll
        for (int nj = 0; nj < 4; ++nj)
          acc[ei][nj] = __builtin_amdgcn_mfma_f32_16x16x32_f16(af[ei], bv[nj],
                                                               acc[ei][nj], 0, 0, 0);
    }

    // in-lane ascending-e top-2 scan (pure VALU), running across slabs
    const int e0w = (w * 2 + et) * 64;
#pragma unroll
    for (int ei = 0; ei < 4; ++ei)
#pragma unroll
      for (int rg = 0; rg < 4; ++rg) {
        int e = e0w + ei * 16 + g * 4 + rg;
        float en = enorm[e];
#pragma unroll
        for (int nj = 0; nj < 4; ++nj) {
          float d = fmaf(NEG2_SCALE, acc[ei][nj][rg], __fadd_rn(zn[nj], en));
          if (d < bd[nj]) {
            b2[nj] = bd[nj]; bd[nj] = d; bi[nj] = e;
          } else if (d < b2[nj]) {
            b2[nj] = d;
          }
        }
      }
  }

  // cross-g butterfly (lanes {l15+16g} share n; disjoint e-subsets)
#pragma unroll
  for (int nj = 0; nj < 4; ++nj) {
#pragma unroll
    for (int m = 16; m <= 32; m <<= 1) {
      float od = __shfl_xor(bd[nj], m, 64);
      int   oi = __shfl_xor(bi[nj], m, 64);
      float o2 = __shfl_xor(b2[nj], m, 64);
      float hi = fmaxf(bd[nj], od);
      b2[nj] = fminf(fminf(b2[nj], o2), hi);
      if (od < bd[nj] || (od == bd[nj] && oi < bi[nj])) { bd[nj] = od; bi[nj] = oi; }
    }
    if (g == 0) {
      int nl = nj * 16 + l15;            // block-local n (0..63)
      sdd[nl][w] = bd[nj];
      sdi[nl][w] = bi[nj];
      sd2[nl][w] = b2[nj];
    }
  }
  __syncthreads();

  // 8-way cross-wave merge (waves e-ordered), exact first-index tie-break;
  // then in-wave loss reduction (tid<64 is exactly wave 0)
  if (t < 64) {
    float bdf = 3.4e38f; int bif = 0x7FFFFFFF; int bw = -1;
#pragma unroll
    for (int ww = 0; ww < 8; ++ww) {
      float d = sdd[t][ww];
      int   i = sdi[t][ww];
      if (d < bdf || (d == bdf && i < bif)) { bdf = d; bif = i; bw = ww; }
    }
    float b2f = 3.4e38f;
#pragma unroll
    for (int ww = 0; ww < 8; ++ww) {
      float v = (ww == bw) ? sd2[t][ww] : sdd[t][ww];
      b2f = fminf(b2f, v);
    }
    int n = n0 + t;
    idx_out[n] = bif;
    if (b2f - bdf < THETA) {
      int p = atomicAdd(flag_cnt, 1);
      flag_list[p] = n;
    }
    float s = bdf;
#pragma unroll
    for (int m = 1; m <= 32; m <<= 1) s += __shfl_xor(s, m, 64);
    if (t == 0) loss_blk[bid] = s;
  }
}

// ---------------------------------------------------------------------------
// coalesced exact-fp32 repair: 4 flagged rows per block share one embT
// stream; per-row fmaf chain identical to the r1-certified arithmetic.
__global__ __launch_bounds__(256) void repair_kernel(
    const float* __restrict__ z, const float* __restrict__ embT,
    const float* __restrict__ znorm, const float* __restrict__ enorm,
    const int* __restrict__ flag_cnt, const int* __restrict__ flag_list,
    int* __restrict__ idx_out) {
  __shared__ float zrow[4][256];
  __shared__ float rd[256];
  __shared__ int   ri[256];
  const int t = threadIdx.x;
  const int cnt = flag_cnt[0] < NROWS ? flag_cnt[0] : NROWS;
  const int nquad = (cnt + 3) >> 2;
  const float4* embT4 = reinterpret_cast<const float4*>(embT);
  for (int j = blockIdx.x; j < nquad; j += gridDim.x) {
    int nr[4];
    __syncthreads();
#pragma unroll
    for (int r = 0; r < 4; ++r) {
      int jr = j * 4 + r;
      nr[r] = flag_list[jr < cnt ? jr : cnt - 1];
      zrow[r][t] = z[(size_t)(nr[r] >> 10) * ZB_STRIDE + (size_t)t * 1024 + (nr[r] & 1023)];
    }
    __syncthreads();
    float4 dot[4] = {{0.f,0.f,0.f,0.f},{0.f,0.f,0.f,0.f},{0.f,0.f,0.f,0.f},{0.f,0.f,0.f,0.f}};
    for (int k = 0; k < 256; ++k) {
      float4 v = embT4[k * 256 + t];
#pragma unroll
      for (int r = 0; r < 4; ++r) {
        float s = zrow[r][k];
        dot[r].x = fmaf(s, v.x, dot[r].x);
        dot[r].y = fmaf(s, v.y, dot[r].y);
        dot[r].z = fmaf(s, v.z, dot[r].z);
        dot[r].w = fmaf(s, v.w, dot[r].w);
      }
    }
#pragma unroll 1
    for (int r = 0; r < 4; ++r) {
      const float zn = znorm[nr[r]];
      float bd = 3.4e38f; int bi = 0;
      const float dv[4] = {dot[r].x, dot[r].y, dot[r].z, dot[r].w};
#pragma unroll
      for (int q = 0; q < 4; ++q) {
        int e = t * 4 + q;
        float d = __fsub_rn(__fadd_rn(zn, enorm[e]), __fmul_rn(2.0f, dv[q]));
        if (d < bd) { bd = d; bi = e; }
      }
      rd[t] = bd; ri[t] = bi;
      __syncthreads();
      for (int s2 = 128; s2 > 0; s2 >>= 1) {
        if (t < s2) {
          float od = rd[t + s2]; int oi = ri[t + s2];
          if (od < rd[t] || (od == rd[t] && oi < ri[t])) { rd[t] = od; ri[t] = oi; }
        }
        __syncthreads();
      }
      if (t == 0) idx_out[nr[r]] = ri[0];
      __syncthreads();
    }
  }
}

// ---------------------------------------------------------------------------
// Fused outputs: all 2048 blocks stream the one-hot; blocks [0,1024) also
// gather z_q via LDS-staged emb rows (coalesced float4 loads AND stores);
// blocks [1024,1152) write idx-as-float + histogram.
__global__ __launch_bounds__(256) void outputs_kernel(const int* __restrict__ idx,
                                                      const float* __restrict__ emb,
                                                      float* __restrict__ out_enc,
                                                      float* __restrict__ out_idxf,
                                                      int* __restrict__ hist,
                                                      float* __restrict__ zq_out) {
  const int t = threadIdx.x;
  for (int i = blockIdx.x * 256 + t; i < NROWS * 256; i += 2048 * 256) {
    int n = i >> 8, j4 = i & 255;
    int e = idx[n];
    float4 v = {0.f, 0.f, 0.f, 0.f};
    if ((e >> 2) == j4) ((float*)&v)[e & 3] = 1.0f;
    reinterpret_cast<float4*>(out_enc)[i] = v;
  }
  if (blockIdx.x < 1024) {
    __shared__ int   sidx[32];
    __shared__ float erow[32][257];
    int b = blockIdx.x >> 5, h = blockIdx.x & 31;
    if (t < 32) sidx[t] = idx[b * 1024 + h * 32 + t];
    __syncthreads();
    const float4* emb4 = reinterpret_cast<const float4*>(emb);
    int rj = t >> 3, v0 = t & 7;
    int er = sidx[rj];
#pragma unroll
    for (int u = 0; u < 8; ++u) {
      int f4 = v0 + 8 * u;
      float4 vv = emb4[(size_t)er * 64 + f4];
      erow[rj][f4 * 4 + 0] = vv.x;
      erow[rj][f4 * 4 + 1] = vv.y;
      erow[rj][f4 * 4 + 2] = vv.z;
      erow[rj][f4 * 4 + 3] = vv.w;
    }
    __syncthreads();
    int w4 = t & 7, cs = t >> 3;
    float4* zq4 = reinterpret_cast<float4*>(zq_out + (size_t)b * ZB_STRIDE + h * 32);
#pragma unroll
    for (int u = 0; u < 8; ++u) {
      int c = cs + 32 * u;
      float4 o = {erow[w4 * 4 + 0][c], erow[w4 * 4 + 1][c],
                  erow[w4 * 4 + 2][c], erow[w4 * 4 + 3][c]};
      zq4[(size_t)c * 256 + w4] = o;
    }
  } else if (blockIdx.x < 1152) {
    int n = (blockIdx.x - 1024) * 256 + t;
    int e = idx[n];
    out_idxf[n] = (float)e;
    atomicAdd(&hist[e], 1);
  }
}

__global__ __launch_bounds__(256) void finalize_kernel(const float* __restrict__ loss_blk,
                                                       const int* __restrict__ hist,
                                                       float* __restrict__ out_loss,
                                                       float* __restrict__ out_perp) {
  __shared__ float red[256];
  int t = threadIdx.x;
  red[t] = loss_blk[t] + loss_blk[t + 256];
  __syncthreads();
  for (int s2 = 128; s2 > 0; s2 >>= 1) {
    if (t < s2) red[t] += red[t + s2];
    __syncthreads();
  }
  if (t == 0) out_loss[0] = 1.25f * (red[0] / 8388608.0f);
  __syncthreads();
  float hs = 0.f;
  for (int i = t; i < 1024; i += 256) {
    float em = (float)hist[i] / 32768.0f;
    hs += em * logf(em + 1e-10f);
  }
  red[t] = hs;
  __syncthreads();
  for (int s2 = 128; s2 > 0; s2 >>= 1) {
    if (t < s2) red[t] += red[t + s2];
    __syncthreads();
  }
  if (t == 0) out_perp[0] = expf(-red[0]);
}

// ---------------------------------------------------------------------------
extern "C" void kernel_launch(void* const* d_in, const int* in_sizes, int n_in,
                              void* d_out, int out_size, void* d_ws, size_t ws_size,
                              hipStream_t stream) {
  const float* z   = (const float*)d_in[0];
  const float* emb = (const float*)d_in[1];
  float* out = (float*)d_out;

  float* out_zq   = out + ZQ_OFF;
  float* out_loss = out + LOSS_OFF;
  float* out_perp = out + PERP_OFF;
  float* out_enc  = out + ENC_OFF;
  float* out_idxf = out + IDX_OFF;

  // workspace (small)
  int*   idx       = (int*)d_ws;                   // 32768
  int*   hist      = idx + NROWS;                  // 1024
  int*   flag_cnt  = hist + NE;                    // 4 (1 used)
  int*   flag_list = flag_cnt + 4;                 // 32768
  float* loss_blk  = (float*)(flag_list + NROWS);  // 512
  float* znorm     = loss_blk + 512;               // 32768
  float* enorm     = znorm + NROWS;                // 1024

  // staging buffers carved from the one-hot output region (overwritten later)
  unsigned short* ef16r = (unsigned short*)(out_enc + 2);    // 262144 u16 (16B-aligned)
  float*          embT  = (float*)(ef16r + (size_t)NE * CDIM);// 262144 f32

  // hist (NE ints) and flag_cnt (adjacent) in one memset
  hipMemsetAsync(hist, 0, (NE + 1) * sizeof(int), stream);

  prep_e<<<388, 256, 0, stream>>>(emb, ef16r, embT, enorm);
  zconv_argmin<<<512, 512, 0, stream>>>(z, ef16r, enorm, znorm,
                                        idx, loss_blk, flag_cnt, flag_list);
  repair_kernel<<<256, 256, 0, stream>>>(z, embT, znorm, enorm, flag_cnt, flag_list, idx);
  outputs_kernel<<<2048, 256, 0, stream>>>(idx, emb, out_enc, out_idxf, hist, out_zq);
  finalize_kernel<<<1, 256, 0, stream>>>(loss_blk, hist, out_loss, out_perp);
}

// Round 17
// 134.451 us; speedup vs baseline: 1.7161x; 1.0029x over previous
//
#include <hip/hip_runtime.h>
#include <math.h>

#define NROWS 32768
#define NE    1024
#define CDIM  256
#define ZB_STRIDE 262144

#define ZQ_OFF   0
#define LOSS_OFF 8388608
#define PERP_OFF 8388609
#define ENC_OFF  8388610
#define IDX_OFF  41943042

#define THETA 1.0e-4f
// e scaled by 2^12 before fp16 conversion; -2*dot = -2^-11 * acc
#define NEG2_SCALE (-0.00048828125f)

typedef _Float16 f16x8 __attribute__((ext_vector_type(8)));
typedef __attribute__((ext_vector_type(4))) float f32x4;
typedef __attribute__((ext_vector_type(8))) unsigned short ushort8;

// RNE float -> fp16 bits
__device__ __forceinline__ unsigned short f2h(float x) {
  _Float16 h = (_Float16)x;
  unsigned short u;
  __builtin_memcpy(&u, &h, 2);
  return u;
}

// ---------------------------------------------------------------------------
// numpy-pairwise-exact sum of squares (stride 1)
__device__ __forceinline__ float np_sumsq_256_s1(const float* __restrict__ base) {
  float tot[2];
#pragma unroll
  for (int hh = 0; hh < 2; ++hh) {
    float r[8];
#pragma unroll
    for (int j = 0; j < 8; ++j) {
      float x = base[hh * 128 + j];
      r[j] = __fmul_rn(x, x);
    }
    for (int i = 8; i < 128; i += 8) {
#pragma unroll
      for (int j = 0; j < 8; ++j) {
        float x = base[hh * 128 + i + j];
        r[j] = __fadd_rn(r[j], __fmul_rn(x, x));
      }
    }
    tot[hh] = __fadd_rn(__fadd_rn(__fadd_rn(r[0], r[1]), __fadd_rn(r[2], r[3])),
                        __fadd_rn(__fadd_rn(r[4], r[5]), __fadd_rn(r[6], r[7])));
  }
  return __fadd_rn(tot[0], tot[1]);
}

// ---------------------------------------------------------------------------
// E prep: blocks [0,128): fp16-fragment convert; [128,384): embT transpose;
// [384,388): enorm. ef16r/embT now live in the out_zq region (written only
// by zq_gather, which runs AFTER repair consumes embT).
__global__ __launch_bounds__(256) void prep_e(const float* __restrict__ emb,
                                              unsigned short* __restrict__ ef16r,
                                              float* __restrict__ embT,
                                              float* __restrict__ enorm) {
  const int bid = blockIdx.x;
  const int t = threadIdx.x;
  if (bid < 128) {
    int cid = bid * 256 + t;             // 0..32767
    int e = cid >> 5, cc = cid & 31;
    int kc = cc >> 2, g = cc & 3;
    int c0 = kc * 32 + g * 8;
    ushort8 o;
#pragma unroll
    for (int el = 0; el < 8; ++el) o[el] = f2h(emb[(size_t)e * 256 + c0 + el] * 4096.0f);
    int et = e >> 7, wcb = (e >> 6) & 1, nj = (e >> 4) & 3, l15e = e & 15;
    size_t chunk = ((((size_t)et * 2 + wcb) * 8 + kc) * 4 + nj) * 64 + (size_t)g * 16 + l15e;
    *reinterpret_cast<ushort8*>(ef16r + (chunk << 3)) = o;
  } else if (bid < 384) {
    __shared__ float tile[32][33];
    int tb = bid - 128;
    int be = tb & 31, bc = tb >> 5;
    int tx = t & 31, ty = t >> 5;
#pragma unroll
    for (int i = 0; i < 4; ++i)
      tile[ty + 8 * i][tx] = emb[(size_t)(be * 32 + ty + 8 * i) * 256 + bc * 32 + tx];
    __syncthreads();
#pragma unroll
    for (int i = 0; i < 4; ++i)
      embT[(size_t)(bc * 32 + ty + 8 * i) * 1024 + be * 32 + tx] = tile[tx][ty + 8 * i];
  } else {
    int n = (bid - 384) * 256 + t;
    enorm[n] = np_sumsq_256_s1(emb + (size_t)n * CDIM);
  }
}

// ---------------------------------------------------------------------------
// Fused convert-z + argmin + one-hot/idxf/hist outputs, v14:
//  * Phases A1-A3, B, merge: identical to r16 (passed, absmax 3.8e-6).
//  * NEW: block stashes its 64 final idx in LDS, then all 512 threads
//    stream the 256KB one-hot slice (r13-proven float4 pattern) -- the
//    134MB write now overlaps other blocks' argmin compute instead of
//    running serially afterwards. idxf + hist atomics done at merge.
//  * Flagged rows are patched later by repair (one-hot flip, idxf, hist).
__global__ __launch_bounds__(512, 4) void zconv_argmin(
    const float* __restrict__ z, const unsigned short* __restrict__ ef16r,
    const float* __restrict__ enorm, float* __restrict__ znorm,
    int* __restrict__ idx_out, float* __restrict__ loss_blk,
    int* __restrict__ flag_cnt, int* __restrict__ flag_list,
    float* __restrict__ out_enc, float* __restrict__ out_idxf,
    int* __restrict__ hist) {
  __shared__ __align__(16) char smA[34048];        // T16 [64][266] u16 / Bfrag 32KB (union)
  __shared__ float accsF[2][8][16][4];
  __shared__ float znl[64];
  __shared__ float sdd[64][8];
  __shared__ float sd2[64][8];
  __shared__ int   sdi[64][8];
  __shared__ int   sidx[64];

  const int t = threadIdx.x;
  const int bid = blockIdx.x;
  const int mb = (bid & 7) * 64 + (bid >> 3);      // n-slab 0..511
  const int n0 = mb * 64;
  const int b = mb >> 4, hwt = mb & 15;
  const int hw0 = hwt * 64;

  unsigned short (*T16)[266] = reinterpret_cast<unsigned short (*)[266]>(smA);
  unsigned short* Bfrag = reinterpret_cast<unsigned short*>(smA);

  // ---- Phase A1 (t<256): read z slab, squares, T16 fill (r4-certified) ----
  if (t < 256) {
    const int hw4 = t & 15;
    const int jj = (t >> 4) & 7;
    const int hh = t >> 7;
    const float* zb = z + (size_t)b * ZB_STRIDE + hw0 + hw4 * 4;
    float rr[4];
#pragma unroll
    for (int i = 0; i < 16; ++i) {
      int c = hh * 128 + jj + 8 * i;
      float4 v = *reinterpret_cast<const float4*>(zb + (size_t)c * 1024);
      const float xv[4] = {v.x, v.y, v.z, v.w};
#pragma unroll
      for (int q = 0; q < 4; ++q) {
        float p = __fmul_rn(xv[q], xv[q]);
        rr[q] = (i == 0) ? p : __fadd_rn(rr[q], p);
        T16[hw4 * 4 + q][c] = f2h(xv[q]);
      }
    }
#pragma unroll
    for (int q = 0; q < 4; ++q) accsF[hh][jj][hw4][q] = rr[q];
  }
  __syncthreads();

  // ---- Phase A2: norms (t<64) + fragment regs from T16 (t<256) ----
  if (t < 64) {
    const int h4 = t >> 2, cq = t & 3;
    float tot[2];
#pragma unroll
    for (int half = 0; half < 2; ++half) {
      float r[8];
#pragma unroll
      for (int j = 0; j < 8; ++j) r[j] = accsF[half][j][h4][cq];
      tot[half] = __fadd_rn(__fadd_rn(__fadd_rn(r[0], r[1]), __fadd_rn(r[2], r[3])),
                            __fadd_rn(__fadd_rn(r[4], r[5]), __fadd_rn(r[6], r[7])));
    }
    float nr = __fadd_rn(tot[0], tot[1]);
    znl[t] = nr;
    znorm[n0 + t] = nr;
  }
  ushort8 fr[8];
  {
    const int l15w = t & 15, gw = (t >> 4) & 3, miw = (t >> 6) & 3;
    const int rowW = miw * 16 + l15w;
    if (t < 256) {
#pragma unroll
      for (int kc = 0; kc < 8; ++kc)
#pragma unroll
        for (int el = 0; el < 8; ++el) fr[kc][el] = T16[rowW][kc * 32 + gw * 8 + el];
    }
  }
  __syncthreads();

  // ---- Phase A3 (t<256): write fragments to Bfrag (over T16 space) ----
  if (t < 256) {
    const int l15w = t & 15, gw = (t >> 4) & 3, miw = (t >> 6) & 3;
#pragma unroll
    for (int kc = 0; kc < 8; ++kc) {
      int chunk = (kc * 4 + miw) * 64 + gw * 16 + l15w;
      *reinterpret_cast<ushort8*>(Bfrag + chunk * 8) = fr[kc];
    }
  }
  __syncthreads();

  // ---- Phase B: 8-wave argmin over all 1024 e; B from LDS ----
  const int lane = t & 63, w = t >> 6;             // w = e-eighth (0..7)
  const int l15 = lane & 15, g = lane >> 4;

  float zn[4];
#pragma unroll
  for (int nj = 0; nj < 4; ++nj) zn[nj] = znl[nj * 16 + l15];

  float bd[4], b2[4]; int bi[4];
#pragma unroll
  for (int nj = 0; nj < 4; ++nj) { bd[nj] = 3.4e38f; b2[nj] = 3.4e38f; bi[nj] = 0; }

  const f32x4 z4 = {0.f, 0.f, 0.f, 0.f};
#pragma unroll 1
  for (int et = 0; et < 2; ++et) {
    const unsigned short* aP = ef16r + (size_t)(w * 2 + et) * 16384 + lane * 8;

    f32x4 acc[4][4];
#pragma unroll
    for (int ei = 0; ei < 4; ++ei)
#pragma unroll
      for (int nj = 0; nj < 4; ++nj) acc[ei][nj] = z4;

#pragma unroll 1
    for (int kc = 0; kc < 8; ++kc) {
      f16x8 af[4], bv[4];
#pragma unroll
      for (int ei = 0; ei < 4; ++ei)
        af[ei] = *reinterpret_cast<const f16x8*>(aP + ei * 512);
#pragma unroll
      for (int nj = 0; nj < 4; ++nj)
        bv[nj] = *reinterpret_cast<const f16x8*>(Bfrag + ((kc * 4 + nj) * 64 + lane) * 8);
      aP += 2048;
#pragma unroll
      for (int ei = 0; ei < 4; ++ei)
#pragma unroll
        for (int nj = 0; nj < 4; ++nj)
          acc[ei][nj] = __builtin_amdgcn_mfma_f32_16x16x32_f16(af[ei], bv[nj],
                                                               acc[ei][nj], 0, 0, 0);
    }

    const int e0w = (w * 2 + et) * 64;
#pragma unroll
    for (int ei = 0; ei < 4; ++ei)
#pragma unroll
      for (int rg = 0; rg < 4; ++rg) {
        int e = e0w + ei * 16 + g * 4 + rg;
        float en = enorm[e];
#pragma unroll
        for (int nj = 0; nj < 4; ++nj) {
          float d = fmaf(NEG2_SCALE, acc[ei][nj][rg], __fadd_rn(zn[nj], en));
          if (d < bd[nj]) {
            b2[nj] = bd[nj]; bd[nj] = d; bi[nj] = e;
          } else if (d < b2[nj]) {
            b2[nj] = d;
          }
        }
      }
  }

  // cross-g butterfly (lanes {l15+16g} share n; disjoint e-subsets)
#pragma unroll
  for (int nj = 0; nj < 4; ++nj) {
#pragma unroll
    for (int m = 16; m <= 32; m <<= 1) {
      float od = __shfl_xor(bd[nj], m, 64);
      int   oi = __shfl_xor(bi[nj], m, 64);
      float o2 = __shfl_xor(b2[nj], m, 64);
      float hi = fmaxf(bd[nj], od);
      b2[nj] = fminf(fminf(b2[nj], o2), hi);
      if (od < bd[nj] || (od == bd[nj] && oi < bi[nj])) { bd[nj] = od; bi[nj] = oi; }
    }
    if (g == 0) {
      int nl = nj * 16 + l15;
      sdd[nl][w] = bd[nj];
      sdi[nl][w] = bi[nj];
      sd2[nl][w] = b2[nj];
    }
  }
  __syncthreads();

  // 8-way e-ordered cross-wave merge; idx/flag/idxf/hist written here
  if (t < 64) {
    float bdf = 3.4e38f; int bif = 0x7FFFFFFF; int bw = -1;
#pragma unroll
    for (int ww = 0; ww < 8; ++ww) {
      float d = sdd[t][ww];
      int   i = sdi[t][ww];
      if (d < bdf || (d == bdf && i < bif)) { bdf = d; bif = i; bw = ww; }
    }
    float b2f = 3.4e38f;
#pragma unroll
    for (int ww = 0; ww < 8; ++ww) {
      float v = (ww == bw) ? sd2[t][ww] : sdd[t][ww];
      b2f = fminf(b2f, v);
    }
    int n = n0 + t;
    idx_out[n] = bif;
    sidx[t] = bif;
    out_idxf[n] = (float)bif;
    atomicAdd(&hist[bif], 1);
    if (b2f - bdf < THETA) {
      int p = atomicAdd(flag_cnt, 1);
      flag_list[p] = n;
    }
    float s = bdf;
#pragma unroll
    for (int m = 1; m <= 32; m <<= 1) s += __shfl_xor(s, m, 64);
    if (t == 0) loss_blk[bid] = s;
  }
  __syncthreads();

  // ---- one-hot stream: 64 rows x 256 float4 = 16384 float4, 32/thread ----
  float4* enc4 = reinterpret_cast<float4*>(out_enc + (size_t)n0 * 1024);
#pragma unroll 4
  for (int i = t; i < 16384; i += 512) {
    int nl = i >> 8, j4 = i & 255;
    int e = sidx[nl];
    float4 v = {0.f, 0.f, 0.f, 0.f};
    if ((e >> 2) == j4) ((float*)&v)[e & 3] = 1.0f;
    enc4[i] = v;
  }
}

// ---------------------------------------------------------------------------
// exact-fp32 repair + output patch: 4 flagged rows per block share one embT
// stream (r1-certified per-row arithmetic); on idx change, flip one-hot
// cells, fix idxf, adjust hist (patches guarded against tail duplicates).
__global__ __launch_bounds__(256) void repair_kernel(
    const float* __restrict__ z, const float* __restrict__ embT,
    const float* __restrict__ znorm, const float* __restrict__ enorm,
    const int* __restrict__ flag_cnt, const int* __restrict__ flag_list,
    int* __restrict__ idx_out, float* __restrict__ out_enc,
    float* __restrict__ out_idxf, int* __restrict__ hist) {
  __shared__ float zrow[4][256];
  __shared__ float rd[256];
  __shared__ int   ri[256];
  const int t = threadIdx.x;
  const int cnt = flag_cnt[0] < NROWS ? flag_cnt[0] : NROWS;
  const int nquad = (cnt + 3) >> 2;
  const float4* embT4 = reinterpret_cast<const float4*>(embT);
  for (int j = blockIdx.x; j < nquad; j += gridDim.x) {
    int nr[4];
    __syncthreads();
#pragma unroll
    for (int r = 0; r < 4; ++r) {
      int jr = j * 4 + r;
      nr[r] = flag_list[jr < cnt ? jr : cnt - 1];
      zrow[r][t] = z[(size_t)(nr[r] >> 10) * ZB_STRIDE + (size_t)t * 1024 + (nr[r] & 1023)];
    }
    __syncthreads();
    float4 dot[4] = {{0.f,0.f,0.f,0.f},{0.f,0.f,0.f,0.f},{0.f,0.f,0.f,0.f},{0.f,0.f,0.f,0.f}};
    for (int k = 0; k < 256; ++k) {
      float4 v = embT4[k * 256 + t];
#pragma unroll
      for (int r = 0; r < 4; ++r) {
        float s = zrow[r][k];
        dot[r].x = fmaf(s, v.x, dot[r].x);
        dot[r].y = fmaf(s, v.y, dot[r].y);
        dot[r].z = fmaf(s, v.z, dot[r].z);
        dot[r].w = fmaf(s, v.w, dot[r].w);
      }
    }
#pragma unroll 1
    for (int r = 0; r < 4; ++r) {
      const float zn = znorm[nr[r]];
      float bd = 3.4e38f; int bi = 0;
      const float dv[4] = {dot[r].x, dot[r].y, dot[r].z, dot[r].w};
#pragma unroll
      for (int q = 0; q < 4; ++q) {
        int e = t * 4 + q;
        float d = __fsub_rn(__fadd_rn(zn, enorm[e]), __fmul_rn(2.0f, dv[q]));
        if (d < bd) { bd = d; bi = e; }
      }
      rd[t] = bd; ri[t] = bi;
      __syncthreads();
      for (int s2 = 128; s2 > 0; s2 >>= 1) {
        if (t < s2) {
          float od = rd[t + s2]; int oi = ri[t + s2];
          if (od < rd[t] || (od == rd[t] && oi < ri[t])) { rd[t] = od; ri[t] = oi; }
        }
        __syncthreads();
      }
      if (t == 0 && (j * 4 + r) < cnt) {
        int n = nr[r];
        int oldv = idx_out[n];
        int newv = ri[0];
        if (newv != oldv) {
          idx_out[n] = newv;
          out_idxf[n] = (float)newv;
          out_enc[(size_t)n * NE + oldv] = 0.f;
          out_enc[(size_t)n * NE + newv] = 1.f;
          atomicAdd(&hist[oldv], -1);
          atomicAdd(&hist[newv], 1);
        }
      }
      __syncthreads();
    }
  }
}

// ---------------------------------------------------------------------------
// z_q gather (runs AFTER repair, uses final idx; overwrites the staging
// that lived in the out_zq region). Exact r16 gather body.
__global__ __launch_bounds__(256) void zq_gather(const int* __restrict__ idx,
                                                 const float* __restrict__ emb,
                                                 float* __restrict__ zq_out) {
  const int t = threadIdx.x;
  __shared__ int   sidx[32];
  __shared__ float erow[32][257];
  int b = blockIdx.x >> 5, h = blockIdx.x & 31;
  if (t < 32) sidx[t] = idx[b * 1024 + h * 32 + t];
  __syncthreads();
  const float4* emb4 = reinterpret_cast<const float4*>(emb);
  int rj = t >> 3, v0 = t & 7;
  int er = sidx[rj];
#pragma unroll
  for (int u = 0; u < 8; ++u) {
    int f4 = v0 + 8 * u;
    float4 vv = emb4[(size_t)er * 64 + f4];
    erow[rj][f4 * 4 + 0] = vv.x;
    erow[rj][f4 * 4 + 1] = vv.y;
    erow[rj][f4 * 4 + 2] = vv.z;
    erow[rj][f4 * 4 + 3] = vv.w;
  }
  __syncthreads();
  int w4 = t & 7, cs = t >> 3;
  float4* zq4 = reinterpret_cast<float4*>(zq_out + (size_t)b * ZB_STRIDE + h * 32);
#pragma unroll
  for (int u = 0; u < 8; ++u) {
    int c = cs + 32 * u;
    float4 o = {erow[w4 * 4 + 0][c], erow[w4 * 4 + 1][c],
                erow[w4 * 4 + 2][c], erow[w4 * 4 + 3][c]};
    zq4[(size_t)c * 256 + w4] = o;
  }
}

__global__ __launch_bounds__(256) void finalize_kernel(const float* __restrict__ loss_blk,
                                                       const int* __restrict__ hist,
                                                       float* __restrict__ out_loss,
                                                       float* __restrict__ out_perp) {
  __shared__ float red[256];
  int t = threadIdx.x;
  red[t] = loss_blk[t] + loss_blk[t + 256];
  __syncthreads();
  for (int s2 = 128; s2 > 0; s2 >>= 1) {
    if (t < s2) red[t] += red[t + s2];
    __syncthreads();
  }
  if (t == 0) out_loss[0] = 1.25f * (red[0] / 8388608.0f);
  __syncthreads();
  float hs = 0.f;
  for (int i = t; i < 1024; i += 256) {
    float em = (float)hist[i] / 32768.0f;
    hs += em * logf(em + 1e-10f);
  }
  red[t] = hs;
  __syncthreads();
  for (int s2 = 128; s2 > 0; s2 >>= 1) {
    if (t < s2) red[t] += red[t + s2];
    __syncthreads();
  }
  if (t == 0) out_perp[0] = expf(-red[0]);
}

// ---------------------------------------------------------------------------
extern "C" void kernel_launch(void* const* d_in, const int* in_sizes, int n_in,
                              void* d_out, int out_size, void* d_ws, size_t ws_size,
                              hipStream_t stream) {
  const float* z   = (const float*)d_in[0];
  const float* emb = (const float*)d_in[1];
  float* out = (float*)d_out;

  float* out_zq   = out + ZQ_OFF;
  float* out_loss = out + LOSS_OFF;
  float* out_perp = out + PERP_OFF;
  float* out_enc  = out + ENC_OFF;
  float* out_idxf = out + IDX_OFF;

  // workspace (small)
  int*   idx       = (int*)d_ws;                   // 32768
  int*   hist      = idx + NROWS;                  // 1024
  int*   flag_cnt  = hist + NE;                    // 4 (1 used)
  int*   flag_list = flag_cnt + 4;                 // 32768
  float* loss_blk  = (float*)(flag_list + NROWS);  // 512
  float* znorm     = loss_blk + 512;               // 32768
  float* enorm     = znorm + NROWS;                // 1024

  // staging now lives in the out_zq region (32MB): consumed by zconv (ef16r)
  // and repair (embT), then overwritten by zq_gather at the end.
  unsigned short* ef16r = (unsigned short*)(out_zq + 2);     // 262144 u16 (16B-aligned phase kept)
  float*          embT  = (float*)(ef16r + (size_t)NE * CDIM);// 262144 f32

  // hist (NE ints) and flag_cnt (adjacent) in one memset
  hipMemsetAsync(hist, 0, (NE + 1) * sizeof(int), stream);

  prep_e<<<388, 256, 0, stream>>>(emb, ef16r, embT, enorm);
  zconv_argmin<<<512, 512, 0, stream>>>(z, ef16r, enorm, znorm,
                                        idx, loss_blk, flag_cnt, flag_list,
                                        out_enc, out_idxf, hist);
  repair_kernel<<<256, 256, 0, stream>>>(z, embT, znorm, enorm, flag_cnt, flag_list,
                                         idx, out_enc, out_idxf, hist);
  zq_gather<<<1024, 256, 0, stream>>>(idx, emb, out_zq);
  finalize_kernel<<<1, 256, 0, stream>>>(loss_blk, hist, out_loss, out_perp);
}